// Round 4
// baseline (626.039 us; speedup 1.0000x reference)
//
#include <hip/hip_runtime.h>
#include <hip/hip_bf16.h>

typedef unsigned short u16;
using f32x4  = __attribute__((ext_vector_type(4))) float;
using bf16x8 = __attribute__((ext_vector_type(8))) short;

typedef __attribute__((address_space(1))) const void global_cvoid;
typedef __attribute__((address_space(3))) void lds_void;

__device__ __forceinline__ void async16(const u16* g, u16* l) {
    // direct global->LDS DMA, 16B per lane, LDS dest = wave-uniform base + lane*16
    __builtin_amdgcn_global_load_lds((global_cvoid*)g, (lds_void*)l, 16, 0, 0);
}

__device__ __forceinline__ u16 f2bf(float f) {
    union { float f; unsigned u; } cv; cv.f = f;
    unsigned r = cv.u + 0x7fff + ((cv.u >> 16) & 1);   // RNE
    return (u16)(r >> 16);
}

// 16-lane-row reductions on the VALU pipe (DPP), not LDS (ds_swizzle)
__device__ __forceinline__ float dppmax16(float x) {
    union { float f; int i; } c, o;
    c.f = x;
    o.i = __builtin_amdgcn_update_dpp(0, c.i, 0xB1,  0xF, 0xF, true); c.f = fmaxf(c.f, o.f); // xor1 (quad_perm 1,0,3,2)
    o.i = __builtin_amdgcn_update_dpp(0, c.i, 0x4E,  0xF, 0xF, true); c.f = fmaxf(c.f, o.f); // xor2 (quad_perm 2,3,0,1)
    o.i = __builtin_amdgcn_update_dpp(0, c.i, 0x141, 0xF, 0xF, true); c.f = fmaxf(c.f, o.f); // row_half_mirror
    o.i = __builtin_amdgcn_update_dpp(0, c.i, 0x140, 0xF, 0xF, true); c.f = fmaxf(c.f, o.f); // row_mirror
    return c.f;
}
__device__ __forceinline__ float dppsum16(float x) {
    union { float f; int i; } c, o;
    c.f = x;
    o.i = __builtin_amdgcn_update_dpp(0, c.i, 0xB1,  0xF, 0xF, true); c.f += o.f;
    o.i = __builtin_amdgcn_update_dpp(0, c.i, 0x4E,  0xF, 0xF, true); c.f += o.f;
    o.i = __builtin_amdgcn_update_dpp(0, c.i, 0x141, 0xF, 0xF, true); c.f += o.f;
    o.i = __builtin_amdgcn_update_dpp(0, c.i, 0x140, 0xF, 0xF, true); c.f += o.f;
    return c.f;
}

// ---------------- cast fp32 -> bf16 (vectorized, memory-bound) ----------------
__global__ __launch_bounds__(256) void cast_kernel(const float* __restrict__ src,
                                                   u16* __restrict__ dst, int n4) {
    int i = blockIdx.x * blockDim.x + threadIdx.x;
    int st = gridDim.x * blockDim.x;
    for (; i < n4; i += st) {
        float4 v = ((const float4*)src)[i];
        ushort4 o;
        o.x = f2bf(v.x); o.y = f2bf(v.y); o.z = f2bf(v.z); o.w = f2bf(v.w);
        ((ushort4*)dst)[i] = o;
    }
}

// ---------------- transpose + cast: fp32 [R][C] -> bf16 [C][R] ----------------
__global__ __launch_bounds__(256) void wtrans_kernel(const float* __restrict__ src,
                                                     u16* __restrict__ dst, int R, int C) {
    __shared__ float tile[64][68];
    int ct = blockIdx.x, rt = blockIdx.y;
    int t = threadIdx.x;
    int r = t >> 2;
    const float* s = src + (size_t)(rt * 64 + r) * C + ct * 64;
#pragma unroll
    for (int jj = 0; jj < 4; ++jj) {
        int c4 = (t & 3) + jj * 4;
        float4 v = *(const float4*)(s + c4 * 4);
        *(float4*)&tile[r][c4 * 4] = v;
    }
    __syncthreads();
    int od = t >> 2;
    u16* d = dst + (size_t)(ct * 64 + od) * R + rt * 64;
#pragma unroll
    for (int jj = 0; jj < 4; ++jj) {
        int c4 = (t & 3) + jj * 4;
        ushort4 v;
        v.x = f2bf(tile[c4 * 4 + 0][od]);
        v.y = f2bf(tile[c4 * 4 + 1][od]);
        v.z = f2bf(tile[c4 * 4 + 2][od]);
        v.w = f2bf(tile[c4 * 4 + 3][od]);
        *(ushort4*)(d + c4 * 4) = v;
    }
}

// ------------- V transpose (bf16->bf16): per (b,h) [1024][192] -> [192][1024] -------------
__global__ __launch_bounds__(256) void vtrans_kernel(const u16* __restrict__ QKV,
                                                     u16* __restrict__ VT) {
    __shared__ u16 tile[64][72];
    int kt = blockIdx.x, dt = blockIdx.y, bh = blockIdx.z;
    int b = bh >> 4, h = bh & 15;
    int t = threadIdx.x;
    int r = t >> 2;
    const u16* src = QKV + ((size_t)(b * 3072 + 2048 + kt * 64)) * 3072 + h * 192 + dt * 64;
#pragma unroll
    for (int jj = 0; jj < 4; ++jj) {
        int c4 = (t & 3) + jj * 4;
        ushort4 v = *(const ushort4*)(src + (size_t)r * 3072 + c4 * 4);
        *(ushort4*)&tile[r][c4 * 4] = v;
    }
    __syncthreads();
    int od = t >> 2;
    u16* dst = VT + ((size_t)(bh * 192 + dt * 64 + od)) * 1024 + kt * 64;
#pragma unroll
    for (int jj = 0; jj < 4; ++jj) {
        int c4 = (t & 3) + jj * 4;
        ushort4 v;
        v.x = tile[c4 * 4 + 0][od];
        v.y = tile[c4 * 4 + 1][od];
        v.z = tile[c4 * 4 + 2][od];
        v.w = tile[c4 * 4 + 3][od];
        *(ushort4*)(dst + c4 * 4) = v;
    }
}

// ---------------- 128x128 bf16 GEMM, B^T input (m97 structure) ----------------
template<bool OUT_F32>
__global__ __launch_bounds__(256, 2)
void gemm_bt_kernel(const u16* __restrict__ A, const u16* __restrict__ BT,
                    void* __restrict__ Cout, const float* __restrict__ bias,
                    int M, int N, int K) {
    __shared__ u16 lA[128 * 64];
    __shared__ u16 lB[128 * 64];
    const int t = threadIdx.x;
    const int w = t >> 6, lane = t & 63;
    const int nbx = N >> 7;
    const int nwg = gridDim.x;
    int bid = blockIdx.x;
    int cpx = nwg >> 3;
    int swz = (bid & 7) * cpx + (bid >> 3);
    const int bx = swz % nbx;
    const int by = swz / nbx;
    const size_t m0 = (size_t)by * 128, n0 = (size_t)bx * 128;

    const int lr = lane >> 3;
    const int lc = (lane & 7) * 8;
    const int wr = (w >> 1) * 64, wc = (w & 1) * 64;

    f32x4 acc[4][4] = {};

    for (int kk = 0; kk < K; kk += 64) {
        __syncthreads();
#pragma unroll
        for (int i = 0; i < 4; ++i) {
            int rr = (w * 4 + i) * 8 + lr;
            async16(A  + (m0 + rr) * (size_t)K + kk + lc, &lA[(w * 4 + i) * 512]);
            async16(BT + (n0 + rr) * (size_t)K + kk + lc, &lB[(w * 4 + i) * 512]);
        }
        __syncthreads();
#pragma unroll
        for (int ks = 0; ks < 2; ++ks) {
            bf16x8 af[4], bfv[4];
#pragma unroll
            for (int m = 0; m < 4; ++m)
                af[m] = *(const bf16x8*)&lA[(wr + m * 16 + (lane & 15)) * 64 + ks * 32 + (lane >> 4) * 8];
#pragma unroll
            for (int n = 0; n < 4; ++n)
                bfv[n] = *(const bf16x8*)&lB[(wc + n * 16 + (lane & 15)) * 64 + ks * 32 + (lane >> 4) * 8];
#pragma unroll
            for (int m = 0; m < 4; ++m)
#pragma unroll
                for (int n = 0; n < 4; ++n)
                    acc[m][n] = __builtin_amdgcn_mfma_f32_16x16x32_bf16(af[m], bfv[n], acc[m][n], 0, 0, 0);
        }
    }

    const int r0 = (lane >> 4) * 4;
    const int cl = lane & 15;
    if constexpr (OUT_F32) {
        float* C = (float*)Cout;
#pragma unroll
        for (int m = 0; m < 4; ++m) {
            size_t row = m0 + wr + m * 16 + r0;
#pragma unroll
            for (int n = 0; n < 4; ++n) {
                size_t col = n0 + wc + n * 16 + cl;
                float bv = bias[col];
#pragma unroll
                for (int r = 0; r < 4; ++r)
                    C[(row + r) * (size_t)N + col] = acc[m][n][r] + bv;
            }
        }
    } else {
        u16* C = (u16*)Cout;
#pragma unroll
        for (int m = 0; m < 4; ++m) {
            size_t row = m0 + wr + m * 16 + r0;
#pragma unroll
            for (int n = 0; n < 4; ++n) {
                size_t col = n0 + wc + n * 16 + cl;
#pragma unroll
                for (int r = 0; r < 4; ++r)
                    C[(row + r) * (size_t)N + col] = f2bf(acc[m][n][r]);
            }
        }
    }
}

// ---------------- flash attention v4 ----------------
// 512 thr (8 waves) x 32 q-rows/wave = 256-row q-tile. K dbuf + V staged in LDS
// (XOR-swizzled, pre-swizzled global src). Shared B-fragment reads across 2
// row-groups halve LDS bytes/FLOP. DPP softmax reductions (VALU pipe).
// Defer-max rescale (THR=8 in exp2 domain).
__global__ __launch_bounds__(512, 2)
void attn_kernel(const u16* __restrict__ QKV, const u16* __restrict__ VT,
                 u16* __restrict__ comb) {
    __shared__ u16 lds[53248];                 // 106496 B: K0|K1|V|P
    u16* lK0 = lds;                            // [64][192] swz (12288 u16)
    u16* lK1 = lds + 12288;
    u16* lV  = lds + 24576;                    // [192][64] swz (12288 u16)
    u16* lP  = lds + 36864;                    // 8 waves x [32][64] swz (16384 u16)

    const int t = threadIdx.x, w = t >> 6, lane = t & 63;
    const int bid = blockIdx.x;                // 512 blocks
    const int gid = (bid & 7) * 64 + (bid >> 3);   // XCD-chunked: 4 q-blocks of a bh share an XCD
    const int bh = gid >> 2, qt = gid & 3;
    const int b = bh >> 4, h = bh & 15;

    const u16* Qg  = QKV + ((size_t)(b * 3072 + qt * 256 + w * 32)) * 3072 + h * 192;
    const u16* Kg  = QKV + ((size_t)(b * 3072 + 1024)) * 3072 + h * 192;
    const u16* VTg = VT + (size_t)bh * 192 * 1024;

    // iteration-invariant pre-swizzled staging offsets (u16 units, 32-bit to save VGPRs)
    unsigned koff[3], voff[3];
#pragma unroll
    for (int i = 0; i < 3; ++i) {
        int ch = i * 512 + t;
        int kr = ch / 24, kc = ch % 24;             // K tile: 64 rows x 24 chunks(16B)
        koff[i] = kr * 3072 + (kc ^ (kr & 7)) * 8;
        int vr = ch >> 3, vc = ch & 7;              // V tile: 192 rows x 8 chunks
        voff[i] = vr * 1024 + (vc ^ (vr & 7)) * 8;
    }

#define STAGE_K(dK, kt) do {                                                      \
    _Pragma("unroll")                                                             \
    for (int i = 0; i < 3; ++i)                                                   \
        async16(Kg + koff[i] + (unsigned)(kt) * 196608u, (dK) + (i * 512 + w * 64) * 8); \
    } while (0)
#define STAGE_V(kt) do {                                                          \
    _Pragma("unroll")                                                             \
    for (int i = 0; i < 3; ++i)                                                   \
        async16(VTg + voff[i] + (unsigned)(kt) * 64u, lV + (i * 512 + w * 64) * 8); \
    } while (0)

    STAGE_K(lK0, 0);

    // Q fragments: direct global->VGPR, 2 row-groups (32 q-rows/wave)
    bf16x8 aq[2][6];
#pragma unroll
    for (int rg = 0; rg < 2; ++rg)
#pragma unroll
        for (int cs = 0; cs < 6; ++cs)
            aq[rg][cs] = *(const bf16x8*)(Qg + (size_t)(rg * 16 + (lane & 15)) * 3072
                                             + cs * 32 + (lane >> 4) * 8);

    f32x4 acc_o[2][12] = {};
    float m2[2][4], lsum[2][4];
#pragma unroll
    for (int rg = 0; rg < 2; ++rg)
#pragma unroll
        for (int r = 0; r < 4; ++r) { m2[rg][r] = -1e30f; lsum[rg][r] = 0.f; }
    const float SC = 0.125f * 1.4426950408889634f;  // scale * log2(e)
    u16* lPw = &lP[w * 2048];

    auto tile_step = [&](int it, u16* Kc, u16* Ka) {
        __syncthreads();                        // A: K[it] ready; prev V reads done
        STAGE_V(it);                            // V latency hides under QK^T+softmax
        if (it + 1 < 16) STAGE_K(Ka, it + 1);   // K prefetch: covered by whole tile

        // S = Q K^T : bk shared across both row-groups
        f32x4 s[2][4] = {};
#pragma unroll
        for (int kf = 0; kf < 4; ++kf) {
            const int krow = kf * 16 + (lane & 15);
#pragma unroll
            for (int cs = 0; cs < 6; ++cs) {
                bf16x8 bk = *(const bf16x8*)&Kc[krow * 192 + ((cs * 4 + (lane >> 4)) ^ (krow & 7)) * 8];
                s[0][kf] = __builtin_amdgcn_mfma_f32_16x16x32_bf16(aq[0][cs], bk, s[0][kf], 0, 0, 0);
                s[1][kf] = __builtin_amdgcn_mfma_f32_16x16x32_bf16(aq[1][cs], bk, s[1][kf], 0, 0, 0);
            }
        }

        // online softmax: DPP 16-lane reductions, defer-max rescale
#pragma unroll
        for (int rg = 0; rg < 2; ++rg) {
#pragma unroll
            for (int kf = 0; kf < 4; ++kf) s[rg][kf] *= SC;
            float mx[4];
            bool need = false;
#pragma unroll
            for (int r = 0; r < 4; ++r) {
                float m = fmaxf(fmaxf(s[rg][0][r], s[rg][1][r]), fmaxf(s[rg][2][r], s[rg][3][r]));
                mx[r] = dppmax16(m);
                need = need || (mx[r] > m2[rg][r] + 8.f);
            }
            if (__any((int)need)) {             // rescale only when max grew enough
#pragma unroll
                for (int r = 0; r < 4; ++r) {
                    float mn = fmaxf(m2[rg][r], mx[r]);
                    float fac = exp2f(m2[rg][r] - mn);
                    m2[rg][r] = mn;
                    lsum[rg][r] *= fac;
#pragma unroll
                    for (int df = 0; df < 12; ++df) acc_o[rg][df][r] *= fac;
                }
            }
#pragma unroll
            for (int r = 0; r < 4; ++r) {
                int q = rg * 16 + (lane >> 4) * 4 + r;
                int xr = (q & 7) << 3;
                float rs = 0.f;
#pragma unroll
                for (int kf = 0; kf < 4; ++kf) {
                    float p = exp2f(s[rg][kf][r] - m2[rg][r]);   // bounded by 2^8
                    rs += p;
                    lPw[q * 64 + ((kf * 16 + (lane & 15)) ^ xr)] = f2bf(p);
                }
                lsum[rg][r] += dppsum16(rs);
            }
        }

        __syncthreads();                        // B: V[it] staged (vmcnt drain)

        // O += P V : bv shared across both row-groups
#pragma unroll
        for (int ks = 0; ks < 2; ++ks) {
            const int prow0 = (lane & 15), prow1 = 16 + (lane & 15);
            const int pcol = ks * 32 + (lane >> 4) * 8;
            bf16x8 pa0 = *(const bf16x8*)&lPw[prow0 * 64 + (pcol ^ ((prow0 & 7) << 3))];
            bf16x8 pa1 = *(const bf16x8*)&lPw[prow1 * 64 + (pcol ^ ((prow1 & 7) << 3))];
#pragma unroll
            for (int df = 0; df < 12; ++df) {
                const int vrow = df * 16 + (lane & 15);
                bf16x8 bv = *(const bf16x8*)&lV[vrow * 64 + ((ks * 4 + (lane >> 4)) ^ (vrow & 7)) * 8];
                acc_o[0][df] = __builtin_amdgcn_mfma_f32_16x16x32_bf16(pa0, bv, acc_o[0][df], 0, 0, 0);
                acc_o[1][df] = __builtin_amdgcn_mfma_f32_16x16x32_bf16(pa1, bv, acc_o[1][df], 0, 0, 0);
            }
        }
    };

#pragma unroll 1
    for (int it2 = 0; it2 < 16; it2 += 2) {
        tile_step(it2,     lK0, lK1);
        tile_step(it2 + 1, lK1, lK0);
    }

    u16* dst = comb + ((size_t)(b * 1024 + qt * 256 + w * 32)) * 3072 + h * 192;
#pragma unroll
    for (int rg = 0; rg < 2; ++rg)
#pragma unroll
        for (int r = 0; r < 4; ++r) {
            int q = rg * 16 + (lane >> 4) * 4 + r;
            float invl = 1.0f / lsum[rg][r];
#pragma unroll
            for (int df = 0; df < 12; ++df)
                dst[(size_t)q * 3072 + df * 16 + (lane & 15)] = f2bf(acc_o[rg][df][r] * invl);
        }
#undef STAGE_K
#undef STAGE_V
}

// ---------------- host ----------------
extern "C" void kernel_launch(void* const* d_in, const int* in_sizes, int n_in,
                              void* d_out, int out_size, void* d_ws, size_t ws_size,
                              hipStream_t stream) {
    const float* X  = (const float*)d_in[0];   // [8,3072,1024]
    const float* W1 = (const float*)d_in[1];   // [1024,3072]
    const float* W2 = (const float*)d_in[2];   // [3072,1024]
    const float* Bb = (const float*)d_in[3];   // [1024]

    char* ws = (char*)d_ws;
    u16* Xb   = (u16*)(ws);                          // 50,331,648 B ; reused as comb
    u16* W1bT = (u16*)(ws + 50331648);               //  6,291,456 B  [3072][1024]
    u16* W2bT = (u16*)(ws + 56623104);               //  6,291,456 B  [1024][3072]
    u16* QKVb = (u16*)(ws + 62914560);               // 150,994,944 B [24576][3072]
    u16* VT   = (u16*)(ws + 213909504);              // 50,331,648 B  [128][192][1024]
    u16* comb = Xb;                                  // [8192][3072]

    cast_kernel<<<2048, 256, 0, stream>>>(X, Xb, (8 * 3072 * 1024) / 4);
    wtrans_kernel<<<dim3(3072 / 64, 1024 / 64), 256, 0, stream>>>(W1, W1bT, 1024, 3072);
    wtrans_kernel<<<dim3(1024 / 64, 3072 / 64), 256, 0, stream>>>(W2, W2bT, 3072, 1024);
    gemm_bt_kernel<false><<<(24576 / 128) * (3072 / 128), 256, 0, stream>>>(
        Xb, W1bT, QKVb, nullptr, 24576, 3072, 1024);
    vtrans_kernel<<<dim3(16, 3, 128), 256, 0, stream>>>(QKVb, VT);
    attn_kernel<<<512, 512, 0, stream>>>(QKVb, VT, comb);
    gemm_bt_kernel<true><<<(8192 / 128) * (1024 / 128), 256, 0, stream>>>(
        comb, W2bT, d_out, Bb, 8192, 1024, 3072);
}

// Round 5
// 537.695 us; speedup vs baseline: 1.1643x; 1.1643x over previous
//
#include <hip/hip_runtime.h>
#include <hip/hip_bf16.h>

typedef unsigned short u16;
using f32x4  = __attribute__((ext_vector_type(4))) float;
using bf16x8 = __attribute__((ext_vector_type(8))) short;

typedef __attribute__((address_space(1))) const void global_cvoid;
typedef __attribute__((address_space(3))) void lds_void;

__device__ __forceinline__ void async16(const u16* g, u16* l) {
    // direct global->LDS DMA, 16B per lane, LDS dest = wave-uniform base + lane*16
    __builtin_amdgcn_global_load_lds((global_cvoid*)g, (lds_void*)l, 16, 0, 0);
}

__device__ __forceinline__ u16 f2bf(float f) {
    union { float f; unsigned u; } cv; cv.f = f;
    unsigned r = cv.u + 0x7fff + ((cv.u >> 16) & 1);   // RNE
    return (u16)(r >> 16);
}

// 16-lane-row reductions on the VALU pipe (DPP), not the LDS pipe
__device__ __forceinline__ float dppmax16(float x) {
    union { float f; int i; } c, o;
    c.f = x;
    o.i = __builtin_amdgcn_update_dpp(0, c.i, 0xB1,  0xF, 0xF, true); c.f = fmaxf(c.f, o.f); // quad_perm 1,0,3,2
    o.i = __builtin_amdgcn_update_dpp(0, c.i, 0x4E,  0xF, 0xF, true); c.f = fmaxf(c.f, o.f); // quad_perm 2,3,0,1
    o.i = __builtin_amdgcn_update_dpp(0, c.i, 0x141, 0xF, 0xF, true); c.f = fmaxf(c.f, o.f); // row_half_mirror
    o.i = __builtin_amdgcn_update_dpp(0, c.i, 0x140, 0xF, 0xF, true); c.f = fmaxf(c.f, o.f); // row_mirror
    return c.f;
}
__device__ __forceinline__ float dppsum16(float x) {
    union { float f; int i; } c, o;
    c.f = x;
    o.i = __builtin_amdgcn_update_dpp(0, c.i, 0xB1,  0xF, 0xF, true); c.f += o.f;
    o.i = __builtin_amdgcn_update_dpp(0, c.i, 0x4E,  0xF, 0xF, true); c.f += o.f;
    o.i = __builtin_amdgcn_update_dpp(0, c.i, 0x141, 0xF, 0xF, true); c.f += o.f;
    o.i = __builtin_amdgcn_update_dpp(0, c.i, 0x140, 0xF, 0xF, true); c.f += o.f;
    return c.f;
}

// ---------------- cast fp32 -> bf16 (vectorized, memory-bound) ----------------
__global__ __launch_bounds__(256) void cast_kernel(const float* __restrict__ src,
                                                   u16* __restrict__ dst, int n4) {
    int i = blockIdx.x * blockDim.x + threadIdx.x;
    int st = gridDim.x * blockDim.x;
    for (; i < n4; i += st) {
        float4 v = ((const float4*)src)[i];
        ushort4 o;
        o.x = f2bf(v.x); o.y = f2bf(v.y); o.z = f2bf(v.z); o.w = f2bf(v.w);
        ((ushort4*)dst)[i] = o;
    }
}

// ---------------- transpose + cast: fp32 [R][C] -> bf16 [C][R] ----------------
__global__ __launch_bounds__(256) void wtrans_kernel(const float* __restrict__ src,
                                                     u16* __restrict__ dst, int R, int C) {
    __shared__ float tile[64][68];
    int ct = blockIdx.x, rt = blockIdx.y;
    int t = threadIdx.x;
    int r = t >> 2;
    const float* s = src + (size_t)(rt * 64 + r) * C + ct * 64;
#pragma unroll
    for (int jj = 0; jj < 4; ++jj) {
        int c4 = (t & 3) + jj * 4;
        float4 v = *(const float4*)(s + c4 * 4);
        *(float4*)&tile[r][c4 * 4] = v;
    }
    __syncthreads();
    int od = t >> 2;
    u16* d = dst + (size_t)(ct * 64 + od) * R + rt * 64;
#pragma unroll
    for (int jj = 0; jj < 4; ++jj) {
        int c4 = (t & 3) + jj * 4;
        ushort4 v;
        v.x = f2bf(tile[c4 * 4 + 0][od]);
        v.y = f2bf(tile[c4 * 4 + 1][od]);
        v.z = f2bf(tile[c4 * 4 + 2][od]);
        v.w = f2bf(tile[c4 * 4 + 3][od]);
        *(ushort4*)(d + c4 * 4) = v;
    }
}

// ------------- V transpose (bf16->bf16): per (b,h) [1024][192] -> [192][1024] -------------
__global__ __launch_bounds__(256) void vtrans_kernel(const u16* __restrict__ QKV,
                                                     u16* __restrict__ VT) {
    __shared__ u16 tile[64][72];
    int kt = blockIdx.x, dt = blockIdx.y, bh = blockIdx.z;
    int b = bh >> 4, h = bh & 15;
    int t = threadIdx.x;
    int r = t >> 2;
    const u16* src = QKV + ((size_t)(b * 3072 + 2048 + kt * 64)) * 3072 + h * 192 + dt * 64;
#pragma unroll
    for (int jj = 0; jj < 4; ++jj) {
        int c4 = (t & 3) + jj * 4;
        ushort4 v = *(const ushort4*)(src + (size_t)r * 3072 + c4 * 4);
        *(ushort4*)&tile[r][c4 * 4] = v;
    }
    __syncthreads();
    int od = t >> 2;
    u16* dst = VT + ((size_t)(bh * 192 + dt * 64 + od)) * 1024 + kt * 64;
#pragma unroll
    for (int jj = 0; jj < 4; ++jj) {
        int c4 = (t & 3) + jj * 4;
        ushort4 v;
        v.x = tile[c4 * 4 + 0][od];
        v.y = tile[c4 * 4 + 1][od];
        v.z = tile[c4 * 4 + 2][od];
        v.w = tile[c4 * 4 + 3][od];
        *(ushort4*)(dst + c4 * 4) = v;
    }
}

// ---------------- 128x128 bf16 GEMM, B^T input (m97 structure) ----------------
template<bool OUT_F32>
__global__ __launch_bounds__(256, 2)
void gemm_bt_kernel(const u16* __restrict__ A, const u16* __restrict__ BT,
                    void* __restrict__ Cout, const float* __restrict__ bias,
                    int M, int N, int K) {
    __shared__ u16 lA[128 * 64];
    __shared__ u16 lB[128 * 64];
    const int t = threadIdx.x;
    const int w = t >> 6, lane = t & 63;
    const int nbx = N >> 7;
    const int nwg = gridDim.x;
    int bid = blockIdx.x;
    int cpx = nwg >> 3;
    int swz = (bid & 7) * cpx + (bid >> 3);
    const int bx = swz % nbx;
    const int by = swz / nbx;
    const size_t m0 = (size_t)by * 128, n0 = (size_t)bx * 128;

    const int lr = lane >> 3;
    const int lc = (lane & 7) * 8;
    const int wr = (w >> 1) * 64, wc = (w & 1) * 64;

    f32x4 acc[4][4] = {};

    for (int kk = 0; kk < K; kk += 64) {
        __syncthreads();
#pragma unroll
        for (int i = 0; i < 4; ++i) {
            int rr = (w * 4 + i) * 8 + lr;
            async16(A  + (m0 + rr) * (size_t)K + kk + lc, &lA[(w * 4 + i) * 512]);
            async16(BT + (n0 + rr) * (size_t)K + kk + lc, &lB[(w * 4 + i) * 512]);
        }
        __syncthreads();
#pragma unroll
        for (int ks = 0; ks < 2; ++ks) {
            bf16x8 af[4], bfv[4];
#pragma unroll
            for (int m = 0; m < 4; ++m)
                af[m] = *(const bf16x8*)&lA[(wr + m * 16 + (lane & 15)) * 64 + ks * 32 + (lane >> 4) * 8];
#pragma unroll
            for (int n = 0; n < 4; ++n)
                bfv[n] = *(const bf16x8*)&lB[(wc + n * 16 + (lane & 15)) * 64 + ks * 32 + (lane >> 4) * 8];
#pragma unroll
            for (int m = 0; m < 4; ++m)
#pragma unroll
                for (int n = 0; n < 4; ++n)
                    acc[m][n] = __builtin_amdgcn_mfma_f32_16x16x32_bf16(af[m], bfv[n], acc[m][n], 0, 0, 0);
        }
    }

    const int r0 = (lane >> 4) * 4;
    const int cl = lane & 15;
    if constexpr (OUT_F32) {
        float* C = (float*)Cout;
#pragma unroll
        for (int m = 0; m < 4; ++m) {
            size_t row = m0 + wr + m * 16 + r0;
#pragma unroll
            for (int n = 0; n < 4; ++n) {
                size_t col = n0 + wc + n * 16 + cl;
                float bv = bias[col];
#pragma unroll
                for (int r = 0; r < 4; ++r)
                    C[(row + r) * (size_t)N + col] = acc[m][n][r] + bv;
            }
        }
    } else {
        u16* C = (u16*)Cout;
#pragma unroll
        for (int m = 0; m < 4; ++m) {
            size_t row = m0 + wr + m * 16 + r0;
#pragma unroll
            for (int n = 0; n < 4; ++n) {
                size_t col = n0 + wc + n * 16 + cl;
#pragma unroll
                for (int r = 0; r < 4; ++r)
                    C[(row + r) * (size_t)N + col] = f2bf(acc[m][n][r]);
            }
        }
    }
}

// ---------------- flash attention v5 ----------------
// 256 thr (4 waves) x 32 q-rows/wave = 128-row q-tile; 2 blocks/CU (64 KiB LDS,
// launch_bounds(256,2) -> 2 waves/SIMD -> 256-VGPR cap, room for rg=2 state).
// Single K and V buffers, race-free prefetch: barrier A -> STAGE_V(t) ->
// QK^T+softmax -> barrier B -> STAGE_K(t+1) -> PV. XOR-swizzled LDS (0 conflicts,
// verified r3). DPP softmax reductions (VALU pipe). Defer-max rescale (THR=8).
__global__ __launch_bounds__(256, 2)
void attn_kernel(const u16* __restrict__ QKV, const u16* __restrict__ VT,
                 u16* __restrict__ comb) {
    __shared__ u16 lds[32768];                 // 65536 B: K|V|P
    u16* lK = lds;                             // [64][192] swz (12288 u16)
    u16* lV = lds + 12288;                     // [192][64] swz (12288 u16)
    u16* lP = lds + 24576;                     // 4 waves x [32][64] swz (8192 u16)

    const int t = threadIdx.x, w = t >> 6, lane = t & 63;
    const int bid = blockIdx.x;                // 1024 blocks
    const int gid = (bid & 7) * 128 + (bid >> 3);   // XCD-chunked: 8 q-blocks of a bh share an XCD
    const int bh = gid >> 3, qt = gid & 7;
    const int b = bh >> 4, h = bh & 15;

    const u16* Qg  = QKV + ((size_t)(b * 3072 + qt * 128 + w * 32)) * 3072 + h * 192;
    const u16* Kg  = QKV + ((size_t)(b * 3072 + 1024)) * 3072 + h * 192;
    const u16* VTg = VT + (size_t)bh * 192 * 1024;

    // iteration-invariant pre-swizzled staging offsets (u16 units)
    unsigned koff[6], voff[6];
#pragma unroll
    for (int i = 0; i < 6; ++i) {
        int ch = i * 256 + t;
        int kr = ch / 24, kc = ch % 24;             // K tile: 64 rows x 24 chunks(16B)
        koff[i] = kr * 3072 + (kc ^ (kr & 7)) * 8;
        int vr = ch >> 3, vc = ch & 7;              // V tile: 192 rows x 8 chunks
        voff[i] = vr * 1024 + (vc ^ (vr & 7)) * 8;
    }

#define STAGE_K(kt) do {                                                          \
    _Pragma("unroll")                                                             \
    for (int i = 0; i < 6; ++i)                                                   \
        async16(Kg + koff[i] + (unsigned)(kt) * 196608u, lK + (i * 256 + w * 64) * 8); \
    } while (0)
#define STAGE_V(kt) do {                                                          \
    _Pragma("unroll")                                                             \
    for (int i = 0; i < 6; ++i)                                                   \
        async16(VTg + voff[i] + (unsigned)(kt) * 64u, lV + (i * 256 + w * 64) * 8); \
    } while (0)

    STAGE_K(0);

    // Q fragments: direct global->VGPR, 2 row-groups (32 q-rows/wave)
    bf16x8 aq[2][6];
#pragma unroll
    for (int rg = 0; rg < 2; ++rg)
#pragma unroll
        for (int cs = 0; cs < 6; ++cs)
            aq[rg][cs] = *(const bf16x8*)(Qg + (size_t)(rg * 16 + (lane & 15)) * 3072
                                             + cs * 32 + (lane >> 4) * 8);

    f32x4 acc_o[2][12] = {};
    float m2[2][4], lsum[2][4];
#pragma unroll
    for (int rg = 0; rg < 2; ++rg)
#pragma unroll
        for (int r = 0; r < 4; ++r) { m2[rg][r] = -1e30f; lsum[rg][r] = 0.f; }
    const float SC = 0.125f * 1.4426950408889634f;  // scale * log2(e)
    u16* lPw = &lP[w * 2048];

#pragma unroll 1
    for (int it = 0; it < 16; ++it) {
        __syncthreads();                        // A: K[it] landed; PV reads of V[it-1] done
        STAGE_V(it);                            // V latency hides under QK^T+softmax

        // S = Q K^T : bk shared across both row-groups
        f32x4 s[2][4] = {};
#pragma unroll
        for (int kf = 0; kf < 4; ++kf) {
            const int krow = kf * 16 + (lane & 15);
#pragma unroll
            for (int cs = 0; cs < 6; ++cs) {
                bf16x8 bk = *(const bf16x8*)&lK[krow * 192 + ((cs * 4 + (lane >> 4)) ^ (krow & 7)) * 8];
                s[0][kf] = __builtin_amdgcn_mfma_f32_16x16x32_bf16(aq[0][cs], bk, s[0][kf], 0, 0, 0);
                s[1][kf] = __builtin_amdgcn_mfma_f32_16x16x32_bf16(aq[1][cs], bk, s[1][kf], 0, 0, 0);
            }
        }

        // online softmax: DPP 16-lane reductions, defer-max rescale
#pragma unroll
        for (int rg = 0; rg < 2; ++rg) {
#pragma unroll
            for (int kf = 0; kf < 4; ++kf) s[rg][kf] *= SC;
            float mx[4];
            bool need = false;
#pragma unroll
            for (int r = 0; r < 4; ++r) {
                float m = fmaxf(fmaxf(s[rg][0][r], s[rg][1][r]), fmaxf(s[rg][2][r], s[rg][3][r]));
                mx[r] = dppmax16(m);
                need = need || (mx[r] > m2[rg][r] + 8.f);
            }
            if (__any((int)need)) {             // rescale only when max grew enough
#pragma unroll
                for (int r = 0; r < 4; ++r) {
                    float mn = fmaxf(m2[rg][r], mx[r]);
                    float fac = exp2f(m2[rg][r] - mn);
                    m2[rg][r] = mn;
                    lsum[rg][r] *= fac;
#pragma unroll
                    for (int df = 0; df < 12; ++df) acc_o[rg][df][r] *= fac;
                }
            }
#pragma unroll
            for (int r = 0; r < 4; ++r) {
                int q = rg * 16 + (lane >> 4) * 4 + r;
                int xr = (q & 7) << 3;
                float rs = 0.f;
#pragma unroll
                for (int kf = 0; kf < 4; ++kf) {
                    float p = exp2f(s[rg][kf][r] - m2[rg][r]);   // bounded by 2^8
                    rs += p;
                    lPw[q * 64 + ((kf * 16 + (lane & 15)) ^ xr)] = f2bf(p);
                }
                lsum[rg][r] += dppsum16(rs);
            }
        }

        __syncthreads();                        // B: V[it] landed; K reads done
        if (it + 1 < 16) STAGE_K(it + 1);       // K latency hides under PV

        // O += P V : bv shared across both row-groups
#pragma unroll
        for (int ks = 0; ks < 2; ++ks) {
            const int prow0 = (lane & 15), prow1 = 16 + (lane & 15);
            const int pcol = ks * 32 + (lane >> 4) * 8;
            bf16x8 pa0 = *(const bf16x8*)&lPw[prow0 * 64 + (pcol ^ ((prow0 & 7) << 3))];
            bf16x8 pa1 = *(const bf16x8*)&lPw[prow1 * 64 + (pcol ^ ((prow1 & 7) << 3))];
#pragma unroll
            for (int df = 0; df < 12; ++df) {
                const int vrow = df * 16 + (lane & 15);
                bf16x8 bv = *(const bf16x8*)&lV[vrow * 64 + ((ks * 4 + (lane >> 4)) ^ (vrow & 7)) * 8];
                acc_o[0][df] = __builtin_amdgcn_mfma_f32_16x16x32_bf16(pa0, bv, acc_o[0][df], 0, 0, 0);
                acc_o[1][df] = __builtin_amdgcn_mfma_f32_16x16x32_bf16(pa1, bv, acc_o[1][df], 0, 0, 0);
            }
        }
    }

    u16* dst = comb + ((size_t)(b * 1024 + qt * 128 + w * 32)) * 3072 + h * 192;
#pragma unroll
    for (int rg = 0; rg < 2; ++rg)
#pragma unroll
        for (int r = 0; r < 4; ++r) {
            int q = rg * 16 + (lane >> 4) * 4 + r;
            float invl = 1.0f / lsum[rg][r];
#pragma unroll
            for (int df = 0; df < 12; ++df)
                dst[(size_t)q * 3072 + df * 16 + (lane & 15)] = f2bf(acc_o[rg][df][r] * invl);
        }
#undef STAGE_K
#undef STAGE_V
}

// ---------------- host ----------------
extern "C" void kernel_launch(void* const* d_in, const int* in_sizes, int n_in,
                              void* d_out, int out_size, void* d_ws, size_t ws_size,
                              hipStream_t stream) {
    const float* X  = (const float*)d_in[0];   // [8,3072,1024]
    const float* W1 = (const float*)d_in[1];   // [1024,3072]
    const float* W2 = (const float*)d_in[2];   // [3072,1024]
    const float* Bb = (const float*)d_in[3];   // [1024]

    char* ws = (char*)d_ws;
    u16* Xb   = (u16*)(ws);                          // 50,331,648 B ; reused as comb
    u16* W1bT = (u16*)(ws + 50331648);               //  6,291,456 B  [3072][1024]
    u16* W2bT = (u16*)(ws + 56623104);               //  6,291,456 B  [1024][3072]
    u16* QKVb = (u16*)(ws + 62914560);               // 150,994,944 B [24576][3072]
    u16* VT   = (u16*)(ws + 213909504);              // 50,331,648 B  [128][192][1024]
    u16* comb = Xb;                                  // [8192][3072]

    cast_kernel<<<2048, 256, 0, stream>>>(X, Xb, (8 * 3072 * 1024) / 4);
    wtrans_kernel<<<dim3(3072 / 64, 1024 / 64), 256, 0, stream>>>(W1, W1bT, 1024, 3072);
    wtrans_kernel<<<dim3(1024 / 64, 3072 / 64), 256, 0, stream>>>(W2, W2bT, 3072, 1024);
    gemm_bt_kernel<false><<<(24576 / 128) * (3072 / 128), 256, 0, stream>>>(
        Xb, W1bT, QKVb, nullptr, 24576, 3072, 1024);
    vtrans_kernel<<<dim3(16, 3, 128), 256, 0, stream>>>(QKVb, VT);
    attn_kernel<<<1024, 256, 0, stream>>>(QKVb, VT, comb);
    gemm_bt_kernel<true><<<(8192 / 128) * (1024 / 128), 256, 0, stream>>>(
        comb, W2bT, d_out, Bb, 8192, 1024, 3072);
}

// Round 8
// 494.500 us; speedup vs baseline: 1.2660x; 1.0874x over previous
//
#include <hip/hip_runtime.h>
#include <hip/hip_bf16.h>

typedef unsigned short u16;
using f32x4  = __attribute__((ext_vector_type(4))) float;
using bf16x8 = __attribute__((ext_vector_type(8))) short;

typedef __attribute__((address_space(1))) const void global_cvoid;
typedef __attribute__((address_space(3))) void lds_void;

__device__ __forceinline__ void async16(const u16* g, u16* l) {
    // direct global->LDS DMA, 16B per lane, LDS dest = wave-uniform base + lane*16
    __builtin_amdgcn_global_load_lds((global_cvoid*)g, (lds_void*)l, 16, 0, 0);
}

__device__ __forceinline__ u16 f2bf(float f) {
    union { float f; unsigned u; } cv; cv.f = f;
    unsigned r = cv.u + 0x7fff + ((cv.u >> 16) & 1);   // RNE
    return (u16)(r >> 16);
}

// 16-lane-row reductions on the VALU pipe (DPP), not the LDS pipe
__device__ __forceinline__ float dppmax16(float x) {
    union { float f; int i; } c, o;
    c.f = x;
    o.i = __builtin_amdgcn_update_dpp(0, c.i, 0xB1,  0xF, 0xF, true); c.f = fmaxf(c.f, o.f); // quad_perm 1,0,3,2
    o.i = __builtin_amdgcn_update_dpp(0, c.i, 0x4E,  0xF, 0xF, true); c.f = fmaxf(c.f, o.f); // quad_perm 2,3,0,1
    o.i = __builtin_amdgcn_update_dpp(0, c.i, 0x141, 0xF, 0xF, true); c.f = fmaxf(c.f, o.f); // row_half_mirror
    o.i = __builtin_amdgcn_update_dpp(0, c.i, 0x140, 0xF, 0xF, true); c.f = fmaxf(c.f, o.f); // row_mirror
    return c.f;
}
__device__ __forceinline__ float dppsum16(float x) {
    union { float f; int i; } c, o;
    c.f = x;
    o.i = __builtin_amdgcn_update_dpp(0, c.i, 0xB1,  0xF, 0xF, true); c.f += o.f;
    o.i = __builtin_amdgcn_update_dpp(0, c.i, 0x4E,  0xF, 0xF, true); c.f += o.f;
    o.i = __builtin_amdgcn_update_dpp(0, c.i, 0x141, 0xF, 0xF, true); c.f += o.f;
    o.i = __builtin_amdgcn_update_dpp(0, c.i, 0x140, 0xF, 0xF, true); c.f += o.f;
    return c.f;
}

// ---------------- cast fp32 -> bf16 (vectorized, memory-bound) ----------------
__global__ __launch_bounds__(256) void cast_kernel(const float* __restrict__ src,
                                                   u16* __restrict__ dst, int n4) {
    int i = blockIdx.x * blockDim.x + threadIdx.x;
    int st = gridDim.x * blockDim.x;
    for (; i < n4; i += st) {
        float4 v = ((const float4*)src)[i];
        ushort4 o;
        o.x = f2bf(v.x); o.y = f2bf(v.y); o.z = f2bf(v.z); o.w = f2bf(v.w);
        ((ushort4*)dst)[i] = o;
    }
}

// ---------------- transpose + cast: fp32 [R][C] -> bf16 [C][R] ----------------
__global__ __launch_bounds__(256) void wtrans_kernel(const float* __restrict__ src,
                                                     u16* __restrict__ dst, int R, int C) {
    __shared__ float tile[64][68];
    int ct = blockIdx.x, rt = blockIdx.y;
    int t = threadIdx.x;
    int r = t >> 2;
    const float* s = src + (size_t)(rt * 64 + r) * C + ct * 64;
#pragma unroll
    for (int jj = 0; jj < 4; ++jj) {
        int c4 = (t & 3) + jj * 4;
        float4 v = *(const float4*)(s + c4 * 4);
        *(float4*)&tile[r][c4 * 4] = v;
    }
    __syncthreads();
    int od = t >> 2;
    u16* d = dst + (size_t)(ct * 64 + od) * R + rt * 64;
#pragma unroll
    for (int jj = 0; jj < 4; ++jj) {
        int c4 = (t & 3) + jj * 4;
        ushort4 v;
        v.x = f2bf(tile[c4 * 4 + 0][od]);
        v.y = f2bf(tile[c4 * 4 + 1][od]);
        v.z = f2bf(tile[c4 * 4 + 2][od]);
        v.w = f2bf(tile[c4 * 4 + 3][od]);
        *(ushort4*)(d + c4 * 4) = v;
    }
}

// ---------------- 128x128 bf16 GEMM, B^T input (m97 structure) ----------------
// OUT_F32: fp32 + bias. Else bf16; if VTout != nullptr, tiles whose token rows
// fall in the V third (tok%3072 >= 2048) are written TRANSPOSED to VT
// [bh][192][1024] instead of to C (fuses the old vtrans kernel).
template<bool OUT_F32>
__global__ __launch_bounds__(256, 2)
void gemm_bt_kernel(const u16* __restrict__ A, const u16* __restrict__ BT,
                    void* __restrict__ Cout, const float* __restrict__ bias,
                    u16* __restrict__ VTout,
                    int M, int N, int K) {
    __shared__ u16 lA[128 * 64];
    __shared__ u16 lB[128 * 64];
    const int t = threadIdx.x;
    const int w = t >> 6, lane = t & 63;
    const int nbx = N >> 7;
    const int nwg = gridDim.x;
    int bid = blockIdx.x;
    int cpx = nwg >> 3;
    int swz = (bid & 7) * cpx + (bid >> 3);
    const int bx = swz % nbx;
    const int by = swz / nbx;
    const size_t m0 = (size_t)by * 128, n0 = (size_t)bx * 128;

    const int lr = lane >> 3;
    const int lc = (lane & 7) * 8;
    const int wr = (w >> 1) * 64, wc = (w & 1) * 64;

    f32x4 acc[4][4] = {};

    for (int kk = 0; kk < K; kk += 64) {
        __syncthreads();
#pragma unroll
        for (int i = 0; i < 4; ++i) {
            int rr = (w * 4 + i) * 8 + lr;
            async16(A  + (m0 + rr) * (size_t)K + kk + lc, &lA[(w * 4 + i) * 512]);
            async16(BT + (n0 + rr) * (size_t)K + kk + lc, &lB[(w * 4 + i) * 512]);
        }
        __syncthreads();
#pragma unroll
        for (int ks = 0; ks < 2; ++ks) {
            bf16x8 af[4], bfv[4];
#pragma unroll
            for (int m = 0; m < 4; ++m)
                af[m] = *(const bf16x8*)&lA[(wr + m * 16 + (lane & 15)) * 64 + ks * 32 + (lane >> 4) * 8];
#pragma unroll
            for (int n = 0; n < 4; ++n)
                bfv[n] = *(const bf16x8*)&lB[(wc + n * 16 + (lane & 15)) * 64 + ks * 32 + (lane >> 4) * 8];
#pragma unroll
            for (int m = 0; m < 4; ++m)
#pragma unroll
                for (int n = 0; n < 4; ++n)
                    acc[m][n] = __builtin_amdgcn_mfma_f32_16x16x32_bf16(af[m], bfv[n], acc[m][n], 0, 0, 0);
        }
    }

    const int r0 = (lane >> 4) * 4;
    const int cl = lane & 15;
    if constexpr (OUT_F32) {
        float* C = (float*)Cout;
#pragma unroll
        for (int m = 0; m < 4; ++m) {
            size_t row = m0 + wr + m * 16 + r0;
#pragma unroll
            for (int n = 0; n < 4; ++n) {
                size_t col = n0 + wc + n * 16 + cl;
                float bv = bias[col];
#pragma unroll
                for (int r = 0; r < 4; ++r)
                    C[(row + r) * (size_t)N + col] = acc[m][n][r] + bv;
            }
        }
    } else {
        int tok0 = (int)(m0 % 3072);
        if (VTout != nullptr && tok0 >= 2048) {
            // transposed V write: VT[(b*16+h)*192 + ch][tok]
            int b = (int)(m0 / 3072);
#pragma unroll
            for (int m = 0; m < 4; ++m) {
                int tok = tok0 - 2048 + wr + m * 16 + r0;
#pragma unroll
                for (int n = 0; n < 4; ++n) {
                    int col = (int)n0 + wc + n * 16 + cl;
                    int h = col / 192, ch = col % 192;
                    ushort4 v;
                    v.x = f2bf(acc[m][n][0]);
                    v.y = f2bf(acc[m][n][1]);
                    v.z = f2bf(acc[m][n][2]);
                    v.w = f2bf(acc[m][n][3]);
                    *(ushort4*)(VTout + ((size_t)(b * 16 + h) * 192 + ch) * 1024 + tok) = v;
                }
            }
        } else {
            u16* C = (u16*)Cout;
#pragma unroll
            for (int m = 0; m < 4; ++m) {
                size_t row = m0 + wr + m * 16 + r0;
#pragma unroll
                for (int n = 0; n < 4; ++n) {
                    size_t col = n0 + wc + n * 16 + cl;
#pragma unroll
                    for (int r = 0; r < 4; ++r)
                        C[(row + r) * (size_t)N + col] = f2bf(acc[m][n][r]);
                }
            }
        }
    }
}

// ---------------- flash attention (r5-verbatim: last PASSING version) ----------------
// 256 thr (4 waves) x 32 q-rows/wave = 128-row q-tile; single K/V buffers,
// race-free prefetch; XOR-swizzled LDS; DPP softmax; defer-8 rescale.
__global__ __launch_bounds__(256, 2)
void attn_kernel(const u16* __restrict__ QKV, const u16* __restrict__ VT,
                 u16* __restrict__ comb) {
    __shared__ u16 lds[32768];                 // 65536 B: K|V|P
    u16* lK = lds;                             // [64][192] swz (12288 u16)
    u16* lV = lds + 12288;                     // [192][64] swz (12288 u16)
    u16* lP = lds + 24576;                     // 4 waves x [32][64] swz (8192 u16)

    const int t = threadIdx.x, w = t >> 6, lane = t & 63;
    const int bid = blockIdx.x;                // 1024 blocks
    const int gid = (bid & 7) * 128 + (bid >> 3);   // XCD-chunked
    const int bh = gid >> 3, qt = gid & 7;
    const int b = bh >> 4, h = bh & 15;

    const u16* Qg  = QKV + ((size_t)(b * 3072 + qt * 128 + w * 32)) * 3072 + h * 192;
    const u16* Kg  = QKV + ((size_t)(b * 3072 + 1024)) * 3072 + h * 192;
    const u16* VTg = VT + (size_t)bh * 192 * 1024;

    // iteration-invariant pre-swizzled staging offsets (u16 units)
    unsigned koff[6], voff[6];
#pragma unroll
    for (int i = 0; i < 6; ++i) {
        int ch = i * 256 + t;
        int kr = ch / 24, kc = ch % 24;             // K tile: 64 rows x 24 chunks(16B)
        koff[i] = kr * 3072 + (kc ^ (kr & 7)) * 8;
        int vr = ch >> 3, vc = ch & 7;              // V tile: 192 rows x 8 chunks
        voff[i] = vr * 1024 + (vc ^ (vr & 7)) * 8;
    }

#define STAGE_K(kt) do {                                                          \
    _Pragma("unroll")                                                             \
    for (int i = 0; i < 6; ++i)                                                   \
        async16(Kg + koff[i] + (unsigned)(kt) * 196608u, lK + (i * 256 + w * 64) * 8); \
    } while (0)
#define STAGE_V(kt) do {                                                          \
    _Pragma("unroll")                                                             \
    for (int i = 0; i < 6; ++i)                                                   \
        async16(VTg + voff[i] + (unsigned)(kt) * 64u, lV + (i * 256 + w * 64) * 8); \
    } while (0)

    STAGE_K(0);

    // Q fragments: direct global->VGPR, 2 row-groups (32 q-rows/wave)
    bf16x8 aq[2][6];
#pragma unroll
    for (int rg = 0; rg < 2; ++rg)
#pragma unroll
        for (int cs = 0; cs < 6; ++cs)
            aq[rg][cs] = *(const bf16x8*)(Qg + (size_t)(rg * 16 + (lane & 15)) * 3072
                                             + cs * 32 + (lane >> 4) * 8);

    f32x4 acc_o[2][12] = {};
    float m2[2][4], lsum[2][4];
#pragma unroll
    for (int rg = 0; rg < 2; ++rg)
#pragma unroll
        for (int r = 0; r < 4; ++r) { m2[rg][r] = -1e30f; lsum[rg][r] = 0.f; }
    const float SC = 0.125f * 1.4426950408889634f;  // scale * log2(e)
    u16* lPw = &lP[w * 2048];

#pragma unroll 1
    for (int it = 0; it < 16; ++it) {
        __syncthreads();                        // A: K[it] landed; PV reads of V[it-1] done
        STAGE_V(it);                            // V latency hides under QK^T+softmax

        // S = Q K^T : bk shared across both row-groups
        f32x4 s[2][4] = {};
#pragma unroll
        for (int kf = 0; kf < 4; ++kf) {
            const int krow = kf * 16 + (lane & 15);
#pragma unroll
            for (int cs = 0; cs < 6; ++cs) {
                bf16x8 bk = *(const bf16x8*)&lK[krow * 192 + ((cs * 4 + (lane >> 4)) ^ (krow & 7)) * 8];
                s[0][kf] = __builtin_amdgcn_mfma_f32_16x16x32_bf16(aq[0][cs], bk, s[0][kf], 0, 0, 0);
                s[1][kf] = __builtin_amdgcn_mfma_f32_16x16x32_bf16(aq[1][cs], bk, s[1][kf], 0, 0, 0);
            }
        }

        // online softmax: DPP 16-lane reductions, defer-max rescale
#pragma unroll
        for (int rg = 0; rg < 2; ++rg) {
#pragma unroll
            for (int kf = 0; kf < 4; ++kf) s[rg][kf] *= SC;
            float mx[4];
            bool need = false;
#pragma unroll
            for (int r = 0; r < 4; ++r) {
                float m = fmaxf(fmaxf(s[rg][0][r], s[rg][1][r]), fmaxf(s[rg][2][r], s[rg][3][r]));
                mx[r] = dppmax16(m);
                need = need || (mx[r] > m2[rg][r] + 8.f);
            }
            if (__any((int)need)) {             // rescale only when max grew enough
#pragma unroll
                for (int r = 0; r < 4; ++r) {
                    float mn = fmaxf(m2[rg][r], mx[r]);
                    float fac = exp2f(m2[rg][r] - mn);
                    m2[rg][r] = mn;
                    lsum[rg][r] *= fac;
#pragma unroll
                    for (int df = 0; df < 12; ++df) acc_o[rg][df][r] *= fac;
                }
            }
#pragma unroll
            for (int r = 0; r < 4; ++r) {
                int q = rg * 16 + (lane >> 4) * 4 + r;
                int xr = (q & 7) << 3;
                float rs = 0.f;
#pragma unroll
                for (int kf = 0; kf < 4; ++kf) {
                    float p = exp2f(s[rg][kf][r] - m2[rg][r]);   // bounded by 2^8
                    rs += p;
                    lPw[q * 64 + ((kf * 16 + (lane & 15)) ^ xr)] = f2bf(p);
                }
                lsum[rg][r] += dppsum16(rs);
            }
        }

        __syncthreads();                        // B: V[it] landed; K reads done
        if (it + 1 < 16) STAGE_K(it + 1);       // K latency hides under PV

        // O += P V : bv shared across both row-groups
#pragma unroll
        for (int ks = 0; ks < 2; ++ks) {
            const int prow0 = (lane & 15), prow1 = 16 + (lane & 15);
            const int pcol = ks * 32 + (lane >> 4) * 8;
            bf16x8 pa0 = *(const bf16x8*)&lPw[prow0 * 64 + (pcol ^ ((prow0 & 7) << 3))];
            bf16x8 pa1 = *(const bf16x8*)&lPw[(prow1) * 64 + (pcol ^ ((prow1 & 7) << 3))];
#pragma unroll
            for (int df = 0; df < 12; ++df) {
                const int vrow = df * 16 + (lane & 15);
                bf16x8 bv = *(const bf16x8*)&lV[vrow * 64 + ((ks * 4 + (lane >> 4)) ^ (vrow & 7)) * 8];
                acc_o[0][df] = __builtin_amdgcn_mfma_f32_16x16x32_bf16(pa0, bv, acc_o[0][df], 0, 0, 0);
                acc_o[1][df] = __builtin_amdgcn_mfma_f32_16x16x32_bf16(pa1, bv, acc_o[1][df], 0, 0, 0);
            }
        }
    }

    u16* dst = comb + ((size_t)(b * 1024 + qt * 128 + w * 32)) * 3072 + h * 192;
#pragma unroll
    for (int rg = 0; rg < 2; ++rg)
#pragma unroll
        for (int r = 0; r < 4; ++r) {
            int q = rg * 16 + (lane >> 4) * 4 + r;
            float invl = 1.0f / lsum[rg][r];
#pragma unroll
            for (int df = 0; df < 12; ++df)
                dst[(size_t)q * 3072 + df * 16 + (lane & 15)] = f2bf(acc_o[rg][df][r] * invl);
        }
#undef STAGE_K
#undef STAGE_V
}

// ---------------- host ----------------
extern "C" void kernel_launch(void* const* d_in, const int* in_sizes, int n_in,
                              void* d_out, int out_size, void* d_ws, size_t ws_size,
                              hipStream_t stream) {
    const float* X  = (const float*)d_in[0];   // [8,3072,1024]
    const float* W1 = (const float*)d_in[1];   // [1024,3072]
    const float* W2 = (const float*)d_in[2];   // [3072,1024]
    const float* Bb = (const float*)d_in[3];   // [1024]

    char* ws = (char*)d_ws;
    u16* Xb   = (u16*)(ws);                          // 50,331,648 B ; reused as comb
    u16* W1bT = (u16*)(ws + 50331648);               //  6,291,456 B  [3072][1024]
    u16* W2bT = (u16*)(ws + 56623104);               //  6,291,456 B  [1024][3072]
    u16* QKVb = (u16*)(ws + 62914560);               // 150,994,944 B [24576][3072] (V third unused)
    u16* VT   = (u16*)(ws + 213909504);              // 50,331,648 B  [128][192][1024]
    u16* comb = Xb;                                  // [8192][3072]

    cast_kernel<<<2048, 256, 0, stream>>>(X, Xb, (8 * 3072 * 1024) / 4);
    wtrans_kernel<<<dim3(3072 / 64, 1024 / 64), 256, 0, stream>>>(W1, W1bT, 1024, 3072);
    wtrans_kernel<<<dim3(1024 / 64, 3072 / 64), 256, 0, stream>>>(W2, W2bT, 3072, 1024);
    // QKV projection; V-third written transposed straight into VT (vtrans fused)
    gemm_bt_kernel<false><<<(24576 / 128) * (3072 / 128), 256, 0, stream>>>(
        Xb, W1bT, QKVb, nullptr, VT, 24576, 3072, 1024);
    attn_kernel<<<1024, 256, 0, stream>>>(QKVb, VT, comb);
    gemm_bt_kernel<true><<<(8192 / 128) * (1024 / 128), 256, 0, stream>>>(
        comb, W2bT, d_out, Bb, nullptr, 8192, 1024, 3072);
}

// Round 9
// 464.340 us; speedup vs baseline: 1.3482x; 1.0650x over previous
//
#include <hip/hip_runtime.h>
#include <hip/hip_bf16.h>

typedef unsigned short u16;
using f32x4  = __attribute__((ext_vector_type(4))) float;
using bf16x8 = __attribute__((ext_vector_type(8))) short;

typedef __attribute__((address_space(1))) const void global_cvoid;
typedef __attribute__((address_space(3))) void lds_void;

__device__ __forceinline__ void async16(const u16* g, u16* l) {
    // direct global->LDS DMA, 16B per lane, LDS dest = wave-uniform base + lane*16
    __builtin_amdgcn_global_load_lds((global_cvoid*)g, (lds_void*)l, 16, 0, 0);
}

__device__ __forceinline__ u16 f2bf(float f) {
    union { float f; unsigned u; } cv; cv.f = f;
    unsigned r = cv.u + 0x7fff + ((cv.u >> 16) & 1);   // RNE
    return (u16)(r >> 16);
}

// truncating bf16 cast (1 op) — used only for attention P values (p > 0,
// bias <= 2^-9 relative; lsum stays fp32-exact so output shift ~0.002 abs)
__device__ __forceinline__ u16 f2bf_rz(float f) {
    union { float f; unsigned u; } cv; cv.f = f;
    return (u16)(cv.u >> 16);
}

// 16-lane-row reductions on the VALU pipe (DPP), not the LDS pipe
__device__ __forceinline__ float dppmax16(float x) {
    union { float f; int i; } c, o;
    c.f = x;
    o.i = __builtin_amdgcn_update_dpp(0, c.i, 0xB1,  0xF, 0xF, true); c.f = fmaxf(c.f, o.f); // quad_perm 1,0,3,2
    o.i = __builtin_amdgcn_update_dpp(0, c.i, 0x4E,  0xF, 0xF, true); c.f = fmaxf(c.f, o.f); // quad_perm 2,3,0,1
    o.i = __builtin_amdgcn_update_dpp(0, c.i, 0x141, 0xF, 0xF, true); c.f = fmaxf(c.f, o.f); // row_half_mirror
    o.i = __builtin_amdgcn_update_dpp(0, c.i, 0x140, 0xF, 0xF, true); c.f = fmaxf(c.f, o.f); // row_mirror
    return c.f;
}
__device__ __forceinline__ float dppsum16(float x) {
    union { float f; int i; } c, o;
    c.f = x;
    o.i = __builtin_amdgcn_update_dpp(0, c.i, 0xB1,  0xF, 0xF, true); c.f += o.f;
    o.i = __builtin_amdgcn_update_dpp(0, c.i, 0x4E,  0xF, 0xF, true); c.f += o.f;
    o.i = __builtin_amdgcn_update_dpp(0, c.i, 0x141, 0xF, 0xF, true); c.f += o.f;
    o.i = __builtin_amdgcn_update_dpp(0, c.i, 0x140, 0xF, 0xF, true); c.f += o.f;
    return c.f;
}

// ---------------- cast fp32 -> bf16 (vectorized, memory-bound) ----------------
__global__ __launch_bounds__(256) void cast_kernel(const float* __restrict__ src,
                                                   u16* __restrict__ dst, int n4) {
    int i = blockIdx.x * blockDim.x + threadIdx.x;
    int st = gridDim.x * blockDim.x;
    for (; i < n4; i += st) {
        float4 v = ((const float4*)src)[i];
        ushort4 o;
        o.x = f2bf(v.x); o.y = f2bf(v.y); o.z = f2bf(v.z); o.w = f2bf(v.w);
        ((ushort4*)dst)[i] = o;
    }
}

// ---------------- transpose + cast: fp32 [R][C] -> bf16 [C][R] ----------------
__global__ __launch_bounds__(256) void wtrans_kernel(const float* __restrict__ src,
                                                     u16* __restrict__ dst, int R, int C) {
    __shared__ float tile[64][68];
    int ct = blockIdx.x, rt = blockIdx.y;
    int t = threadIdx.x;
    int r = t >> 2;
    const float* s = src + (size_t)(rt * 64 + r) * C + ct * 64;
#pragma unroll
    for (int jj = 0; jj < 4; ++jj) {
        int c4 = (t & 3) + jj * 4;
        float4 v = *(const float4*)(s + c4 * 4);
        *(float4*)&tile[r][c4 * 4] = v;
    }
    __syncthreads();
    int od = t >> 2;
    u16* d = dst + (size_t)(ct * 64 + od) * R + rt * 64;
#pragma unroll
    for (int jj = 0; jj < 4; ++jj) {
        int c4 = (t & 3) + jj * 4;
        ushort4 v;
        v.x = f2bf(tile[c4 * 4 + 0][od]);
        v.y = f2bf(tile[c4 * 4 + 1][od]);
        v.z = f2bf(tile[c4 * 4 + 2][od]);
        v.w = f2bf(tile[c4 * 4 + 3][od]);
        *(ushort4*)(d + c4 * 4) = v;
    }
}

// ---------------- 128x128 bf16 GEMM, B^T input (m97 structure) ----------------
// OUT_F32: fp32 + bias. Else bf16; if VTout != nullptr (GEMM1/QKV call):
//   - tok%3072 >= 2048 (V third): written TRANSPOSED to VT [bh][192][1024]
//   - tok%3072 <  1024 (Q third): pre-scaled by 0.125*log2(e) so attention's
//     softmax works directly in the exp2 domain with no per-tile multiply
template<bool OUT_F32>
__global__ __launch_bounds__(256, 2)
void gemm_bt_kernel(const u16* __restrict__ A, const u16* __restrict__ BT,
                    void* __restrict__ Cout, const float* __restrict__ bias,
                    u16* __restrict__ VTout,
                    int M, int N, int K) {
    __shared__ u16 lA[128 * 64];
    __shared__ u16 lB[128 * 64];
    const int t = threadIdx.x;
    const int w = t >> 6, lane = t & 63;
    const int nbx = N >> 7;
    const int nwg = gridDim.x;
    int bid = blockIdx.x;
    int cpx = nwg >> 3;
    int swz = (bid & 7) * cpx + (bid >> 3);
    const int bx = swz % nbx;
    const int by = swz / nbx;
    const size_t m0 = (size_t)by * 128, n0 = (size_t)bx * 128;

    const int lr = lane >> 3;
    const int lc = (lane & 7) * 8;
    const int wr = (w >> 1) * 64, wc = (w & 1) * 64;

    f32x4 acc[4][4] = {};

    for (int kk = 0; kk < K; kk += 64) {
        __syncthreads();
#pragma unroll
        for (int i = 0; i < 4; ++i) {
            int rr = (w * 4 + i) * 8 + lr;
            async16(A  + (m0 + rr) * (size_t)K + kk + lc, &lA[(w * 4 + i) * 512]);
            async16(BT + (n0 + rr) * (size_t)K + kk + lc, &lB[(w * 4 + i) * 512]);
        }
        __syncthreads();
#pragma unroll
        for (int ks = 0; ks < 2; ++ks) {
            bf16x8 af[4], bfv[4];
#pragma unroll
            for (int m = 0; m < 4; ++m)
                af[m] = *(const bf16x8*)&lA[(wr + m * 16 + (lane & 15)) * 64 + ks * 32 + (lane >> 4) * 8];
#pragma unroll
            for (int n = 0; n < 4; ++n)
                bfv[n] = *(const bf16x8*)&lB[(wc + n * 16 + (lane & 15)) * 64 + ks * 32 + (lane >> 4) * 8];
#pragma unroll
            for (int m = 0; m < 4; ++m)
#pragma unroll
                for (int n = 0; n < 4; ++n)
                    acc[m][n] = __builtin_amdgcn_mfma_f32_16x16x32_bf16(af[m], bfv[n], acc[m][n], 0, 0, 0);
        }
    }

    const int r0 = (lane >> 4) * 4;
    const int cl = lane & 15;
    if constexpr (OUT_F32) {
        float* C = (float*)Cout;
#pragma unroll
        for (int m = 0; m < 4; ++m) {
            size_t row = m0 + wr + m * 16 + r0;
#pragma unroll
            for (int n = 0; n < 4; ++n) {
                size_t col = n0 + wc + n * 16 + cl;
                float bv = bias[col];
#pragma unroll
                for (int r = 0; r < 4; ++r)
                    C[(row + r) * (size_t)N + col] = acc[m][n][r] + bv;
            }
        }
    } else {
        int tok0 = (int)(m0 % 3072);
        if (VTout != nullptr && tok0 >= 2048) {
            // transposed V write: VT[(b*16+h)*192 + ch][tok]
            int b = (int)(m0 / 3072);
#pragma unroll
            for (int m = 0; m < 4; ++m) {
                int tok = tok0 - 2048 + wr + m * 16 + r0;
#pragma unroll
                for (int n = 0; n < 4; ++n) {
                    int col = (int)n0 + wc + n * 16 + cl;
                    int h = col / 192, ch = col % 192;
                    ushort4 v;
                    v.x = f2bf(acc[m][n][0]);
                    v.y = f2bf(acc[m][n][1]);
                    v.z = f2bf(acc[m][n][2]);
                    v.w = f2bf(acc[m][n][3]);
                    *(ushort4*)(VTout + ((size_t)(b * 16 + h) * 192 + ch) * 1024 + tok) = v;
                }
            }
        } else {
            // Q-region tiles get the softmax scale folded in (SC = 0.125*log2 e)
            float qs = (VTout != nullptr && tok0 < 1024) ? 0.1803368801111f : 1.0f;
            u16* C = (u16*)Cout;
#pragma unroll
            for (int m = 0; m < 4; ++m) {
                size_t row = m0 + wr + m * 16 + r0;
#pragma unroll
                for (int n = 0; n < 4; ++n) {
                    size_t col = n0 + wc + n * 16 + cl;
#pragma unroll
                    for (int r = 0; r < 4; ++r)
                        C[(row + r) * (size_t)N + col] = f2bf(acc[m][n][r] * qs);
                }
            }
        }
    }
}

// ---------------- flash attention (r5/r8 structure + T5 setprio + SC-folded Q
//                  + truncating P cast) ----------------
// 256 thr (4 waves) x 32 q-rows/wave = 128-row q-tile; single K/V buffers,
// race-free prefetch; XOR-swizzled LDS (0 conflicts); DPP softmax; defer-8.
// Q was pre-scaled by 0.125*log2(e) in the GEMM1 epilogue, so S comes out of
// the MFMA already in the exp2 domain.
__global__ __launch_bounds__(256, 2)
void attn_kernel(const u16* __restrict__ QKV, const u16* __restrict__ VT,
                 u16* __restrict__ comb) {
    __shared__ u16 lds[32768];                 // 65536 B: K|V|P
    u16* lK = lds;                             // [64][192] swz (12288 u16)
    u16* lV = lds + 12288;                     // [192][64] swz (12288 u16)
    u16* lP = lds + 24576;                     // 4 waves x [32][64] swz (8192 u16)

    const int t = threadIdx.x, w = t >> 6, lane = t & 63;
    const int bid = blockIdx.x;                // 1024 blocks
    const int gid = (bid & 7) * 128 + (bid >> 3);   // XCD-chunked
    const int bh = gid >> 3, qt = gid & 7;
    const int b = bh >> 4, h = bh & 15;

    const u16* Qg  = QKV + ((size_t)(b * 3072 + qt * 128 + w * 32)) * 3072 + h * 192;
    const u16* Kg  = QKV + ((size_t)(b * 3072 + 1024)) * 3072 + h * 192;
    const u16* VTg = VT + (size_t)bh * 192 * 1024;

    // iteration-invariant pre-swizzled staging offsets (u16 units)
    unsigned koff[6], voff[6];
#pragma unroll
    for (int i = 0; i < 6; ++i) {
        int ch = i * 256 + t;
        int kr = ch / 24, kc = ch % 24;             // K tile: 64 rows x 24 chunks(16B)
        koff[i] = kr * 3072 + (kc ^ (kr & 7)) * 8;
        int vr = ch >> 3, vc = ch & 7;              // V tile: 192 rows x 8 chunks
        voff[i] = vr * 1024 + (vc ^ (vr & 7)) * 8;
    }

#define STAGE_K(kt) do {                                                          \
    _Pragma("unroll")                                                             \
    for (int i = 0; i < 6; ++i)                                                   \
        async16(Kg + koff[i] + (unsigned)(kt) * 196608u, lK + (i * 256 + w * 64) * 8); \
    } while (0)
#define STAGE_V(kt) do {                                                          \
    _Pragma("unroll")                                                             \
    for (int i = 0; i < 6; ++i)                                                   \
        async16(VTg + voff[i] + (unsigned)(kt) * 64u, lV + (i * 256 + w * 64) * 8); \
    } while (0)

    STAGE_K(0);

    // Q fragments: direct global->VGPR, 2 row-groups (32 q-rows/wave)
    bf16x8 aq[2][6];
#pragma unroll
    for (int rg = 0; rg < 2; ++rg)
#pragma unroll
        for (int cs = 0; cs < 6; ++cs)
            aq[rg][cs] = *(const bf16x8*)(Qg + (size_t)(rg * 16 + (lane & 15)) * 3072
                                             + cs * 32 + (lane >> 4) * 8);

    f32x4 acc_o[2][12] = {};
    float m2[2][4], lsum[2][4];
#pragma unroll
    for (int rg = 0; rg < 2; ++rg)
#pragma unroll
        for (int r = 0; r < 4; ++r) { m2[rg][r] = -1e30f; lsum[rg][r] = 0.f; }
    u16* lPw = &lP[w * 2048];

#pragma unroll 1
    for (int it = 0; it < 16; ++it) {
        __syncthreads();                        // A: K[it] landed; PV reads of V[it-1] done
        STAGE_V(it);                            // V latency hides under QK^T+softmax

        // S = Q K^T : bk shared across both row-groups (already exp2-domain)
        f32x4 s[2][4] = {};
        __builtin_amdgcn_s_setprio(1);
#pragma unroll
        for (int kf = 0; kf < 4; ++kf) {
            const int krow = kf * 16 + (lane & 15);
#pragma unroll
            for (int cs = 0; cs < 6; ++cs) {
                bf16x8 bk = *(const bf16x8*)&lK[krow * 192 + ((cs * 4 + (lane >> 4)) ^ (krow & 7)) * 8];
                s[0][kf] = __builtin_amdgcn_mfma_f32_16x16x32_bf16(aq[0][cs], bk, s[0][kf], 0, 0, 0);
                s[1][kf] = __builtin_amdgcn_mfma_f32_16x16x32_bf16(aq[1][cs], bk, s[1][kf], 0, 0, 0);
            }
        }
        __builtin_amdgcn_s_setprio(0);

        // online softmax: DPP 16-lane reductions, defer-max rescale
#pragma unroll
        for (int rg = 0; rg < 2; ++rg) {
            float mx[4];
            bool need = false;
#pragma unroll
            for (int r = 0; r < 4; ++r) {
                float m = fmaxf(fmaxf(s[rg][0][r], s[rg][1][r]), fmaxf(s[rg][2][r], s[rg][3][r]));
                mx[r] = dppmax16(m);
                need = need || (mx[r] > m2[rg][r] + 8.f);
            }
            if (__any((int)need)) {             // rescale only when max grew enough
#pragma unroll
                for (int r = 0; r < 4; ++r) {
                    float mn = fmaxf(m2[rg][r], mx[r]);
                    float fac = exp2f(m2[rg][r] - mn);
                    m2[rg][r] = mn;
                    lsum[rg][r] *= fac;
#pragma unroll
                    for (int df = 0; df < 12; ++df) acc_o[rg][df][r] *= fac;
                }
            }
#pragma unroll
            for (int r = 0; r < 4; ++r) {
                int q = rg * 16 + (lane >> 4) * 4 + r;
                int xr = (q & 7) << 3;
                float rs = 0.f;
#pragma unroll
                for (int kf = 0; kf < 4; ++kf) {
                    float p = exp2f(s[rg][kf][r] - m2[rg][r]);   // bounded by 2^8
                    rs += p;
                    lPw[q * 64 + ((kf * 16 + (lane & 15)) ^ xr)] = f2bf_rz(p);
                }
                lsum[rg][r] += dppsum16(rs);
            }
        }

        __syncthreads();                        // B: V[it] landed; K reads done
        if (it + 1 < 16) STAGE_K(it + 1);       // K latency hides under PV

        // O += P V : bv shared across both row-groups
        __builtin_amdgcn_s_setprio(1);
#pragma unroll
        for (int ks = 0; ks < 2; ++ks) {
            const int prow0 = (lane & 15), prow1 = 16 + (lane & 15);
            const int pcol = ks * 32 + (lane >> 4) * 8;
            bf16x8 pa0 = *(const bf16x8*)&lPw[prow0 * 64 + (pcol ^ ((prow0 & 7) << 3))];
            bf16x8 pa1 = *(const bf16x8*)&lPw[(prow1) * 64 + (pcol ^ ((prow1 & 7) << 3))];
#pragma unroll
            for (int df = 0; df < 12; ++df) {
                const int vrow = df * 16 + (lane & 15);
                bf16x8 bv = *(const bf16x8*)&lV[vrow * 64 + ((ks * 4 + (lane >> 4)) ^ (vrow & 7)) * 8];
                acc_o[0][df] = __builtin_amdgcn_mfma_f32_16x16x32_bf16(pa0, bv, acc_o[0][df], 0, 0, 0);
                acc_o[1][df] = __builtin_amdgcn_mfma_f32_16x16x32_bf16(pa1, bv, acc_o[1][df], 0, 0, 0);
            }
        }
        __builtin_amdgcn_s_setprio(0);
    }

    u16* dst = comb + ((size_t)(b * 1024 + qt * 128 + w * 32)) * 3072 + h * 192;
#pragma unroll
    for (int rg = 0; rg < 2; ++rg)
#pragma unroll
        for (int r = 0; r < 4; ++r) {
            int q = rg * 16 + (lane >> 4) * 4 + r;
            float invl = 1.0f / lsum[rg][r];
#pragma unroll
            for (int df = 0; df < 12; ++df)
                dst[(size_t)q * 3072 + df * 16 + (lane & 15)] = f2bf(acc_o[rg][df][r] * invl);
        }
#undef STAGE_K
#undef STAGE_V
}

// ---------------- host ----------------
extern "C" void kernel_launch(void* const* d_in, const int* in_sizes, int n_in,
                              void* d_out, int out_size, void* d_ws, size_t ws_size,
                              hipStream_t stream) {
    const float* X  = (const float*)d_in[0];   // [8,3072,1024]
    const float* W1 = (const float*)d_in[1];   // [1024,3072]
    const float* W2 = (const float*)d_in[2];   // [3072,1024]
    const float* Bb = (const float*)d_in[3];   // [1024]

    char* ws = (char*)d_ws;
    u16* Xb   = (u16*)(ws);                          // 50,331,648 B ; reused as comb
    u16* W1bT = (u16*)(ws + 50331648);               //  6,291,456 B  [3072][1024]
    u16* W2bT = (u16*)(ws + 56623104);               //  6,291,456 B  [1024][3072]
    u16* QKVb = (u16*)(ws + 62914560);               // 150,994,944 B [24576][3072] (V third unused)
    u16* VT   = (u16*)(ws + 213909504);              // 50,331,648 B  [128][192][1024]
    u16* comb = Xb;                                  // [8192][3072]

    cast_kernel<<<2048, 256, 0, stream>>>(X, Xb, (8 * 3072 * 1024) / 4);
    wtrans_kernel<<<dim3(3072 / 64, 1024 / 64), 256, 0, stream>>>(W1, W1bT, 1024, 3072);
    wtrans_kernel<<<dim3(1024 / 64, 3072 / 64), 256, 0, stream>>>(W2, W2bT, 3072, 1024);
    // QKV projection; V-third written transposed straight into VT (vtrans fused),
    // Q-third pre-scaled by 0.125*log2(e)
    gemm_bt_kernel<false><<<(24576 / 128) * (3072 / 128), 256, 0, stream>>>(
        Xb, W1bT, QKVb, nullptr, VT, 24576, 3072, 1024);
    attn_kernel<<<1024, 256, 0, stream>>>(QKVb, VT, comb);
    gemm_bt_kernel<true><<<(8192 / 128) * (1024 / 128), 256, 0, stream>>>(
        comb, W2bT, d_out, Bb, nullptr, 8192, 1024, 3072);
}

// Round 10
// 447.766 us; speedup vs baseline: 1.3981x; 1.0370x over previous
//
#include <hip/hip_runtime.h>
#include <hip/hip_bf16.h>

typedef unsigned short u16;
using f32x4  = __attribute__((ext_vector_type(4))) float;
using bf16x8 = __attribute__((ext_vector_type(8))) short;

typedef __attribute__((address_space(1))) const void global_cvoid;
typedef __attribute__((address_space(3))) void lds_void;

__device__ __forceinline__ void async16(const u16* g, u16* l) {
    // direct global->LDS DMA, 16B per lane, LDS dest = wave-uniform base + lane*16
    __builtin_amdgcn_global_load_lds((global_cvoid*)g, (lds_void*)l, 16, 0, 0);
}

__device__ __forceinline__ u16 f2bf(float f) {
    union { float f; unsigned u; } cv; cv.f = f;
    unsigned r = cv.u + 0x7fff + ((cv.u >> 16) & 1);   // RNE
    return (u16)(r >> 16);
}

// truncating bf16 cast (1 op) — attention P values only
__device__ __forceinline__ u16 f2bf_rz(float f) {
    union { float f; unsigned u; } cv; cv.f = f;
    return (u16)(cv.u >> 16);
}

// 16-lane-row reductions on the VALU pipe (DPP), not the LDS pipe
__device__ __forceinline__ float dppmax16(float x) {
    union { float f; int i; } c, o;
    c.f = x;
    o.i = __builtin_amdgcn_update_dpp(0, c.i, 0xB1,  0xF, 0xF, true); c.f = fmaxf(c.f, o.f);
    o.i = __builtin_amdgcn_update_dpp(0, c.i, 0x4E,  0xF, 0xF, true); c.f = fmaxf(c.f, o.f);
    o.i = __builtin_amdgcn_update_dpp(0, c.i, 0x141, 0xF, 0xF, true); c.f = fmaxf(c.f, o.f);
    o.i = __builtin_amdgcn_update_dpp(0, c.i, 0x140, 0xF, 0xF, true); c.f = fmaxf(c.f, o.f);
    return c.f;
}
__device__ __forceinline__ float dppsum16(float x) {
    union { float f; int i; } c, o;
    c.f = x;
    o.i = __builtin_amdgcn_update_dpp(0, c.i, 0xB1,  0xF, 0xF, true); c.f += o.f;
    o.i = __builtin_amdgcn_update_dpp(0, c.i, 0x4E,  0xF, 0xF, true); c.f += o.f;
    o.i = __builtin_amdgcn_update_dpp(0, c.i, 0x141, 0xF, 0xF, true); c.f += o.f;
    o.i = __builtin_amdgcn_update_dpp(0, c.i, 0x140, 0xF, 0xF, true); c.f += o.f;
    return c.f;
}

// ---------------- cast fp32 -> bf16 ----------------
__global__ __launch_bounds__(256) void cast_kernel(const float* __restrict__ src,
                                                   u16* __restrict__ dst, int n4) {
    int i = blockIdx.x * blockDim.x + threadIdx.x;
    int st = gridDim.x * blockDim.x;
    for (; i < n4; i += st) {
        float4 v = ((const float4*)src)[i];
        ushort4 o;
        o.x = f2bf(v.x); o.y = f2bf(v.y); o.z = f2bf(v.z); o.w = f2bf(v.w);
        ((ushort4*)dst)[i] = o;
    }
}

// ---------------- transpose + cast: fp32 [R][C] -> bf16 [C][R] ----------------
__global__ __launch_bounds__(256) void wtrans_kernel(const float* __restrict__ src,
                                                     u16* __restrict__ dst, int R, int C) {
    __shared__ float tile[64][68];
    int ct = blockIdx.x, rt = blockIdx.y;
    int t = threadIdx.x;
    int r = t >> 2;
    const float* s = src + (size_t)(rt * 64 + r) * C + ct * 64;
#pragma unroll
    for (int jj = 0; jj < 4; ++jj) {
        int c4 = (t & 3) + jj * 4;
        float4 v = *(const float4*)(s + c4 * 4);
        *(float4*)&tile[r][c4 * 4] = v;
    }
    __syncthreads();
    int od = t >> 2;
    u16* d = dst + (size_t)(ct * 64 + od) * R + rt * 64;
#pragma unroll
    for (int jj = 0; jj < 4; ++jj) {
        int c4 = (t & 3) + jj * 4;
        ushort4 v;
        v.x = f2bf(tile[c4 * 4 + 0][od]);
        v.y = f2bf(tile[c4 * 4 + 1][od]);
        v.z = f2bf(tile[c4 * 4 + 2][od]);
        v.w = f2bf(tile[c4 * 4 + 3][od]);
        *(ushort4*)(d + c4 * 4) = v;
    }
}

// ---------------- 128x128 bf16 GEMM (m97 structure) — used for GEMM2 only ----------------
template<bool OUT_F32>
__global__ __launch_bounds__(256, 2)
void gemm_bt_kernel(const u16* __restrict__ A, const u16* __restrict__ BT,
                    void* __restrict__ Cout, const float* __restrict__ bias,
                    u16* __restrict__ VTout,
                    int M, int N, int K) {
    __shared__ u16 lA[128 * 64];
    __shared__ u16 lB[128 * 64];
    const int t = threadIdx.x;
    const int w = t >> 6, lane = t & 63;
    const int nbx = N >> 7;
    const int nwg = gridDim.x;
    int bid = blockIdx.x;
    int cpx = nwg >> 3;
    int swz = (bid & 7) * cpx + (bid >> 3);
    const int bx = swz % nbx;
    const int by = swz / nbx;
    const size_t m0 = (size_t)by * 128, n0 = (size_t)bx * 128;

    const int lr = lane >> 3;
    const int lc = (lane & 7) * 8;
    const int wr = (w >> 1) * 64, wc = (w & 1) * 64;

    f32x4 acc[4][4] = {};

    for (int kk = 0; kk < K; kk += 64) {
        __syncthreads();
#pragma unroll
        for (int i = 0; i < 4; ++i) {
            int rr = (w * 4 + i) * 8 + lr;
            async16(A  + (m0 + rr) * (size_t)K + kk + lc, &lA[(w * 4 + i) * 512]);
            async16(BT + (n0 + rr) * (size_t)K + kk + lc, &lB[(w * 4 + i) * 512]);
        }
        __syncthreads();
#pragma unroll
        for (int ks = 0; ks < 2; ++ks) {
            bf16x8 af[4], bfv[4];
#pragma unroll
            for (int m = 0; m < 4; ++m)
                af[m] = *(const bf16x8*)&lA[(wr + m * 16 + (lane & 15)) * 64 + ks * 32 + (lane >> 4) * 8];
#pragma unroll
            for (int n = 0; n < 4; ++n)
                bfv[n] = *(const bf16x8*)&lB[(wc + n * 16 + (lane & 15)) * 64 + ks * 32 + (lane >> 4) * 8];
#pragma unroll
            for (int m = 0; m < 4; ++m)
#pragma unroll
                for (int n = 0; n < 4; ++n)
                    acc[m][n] = __builtin_amdgcn_mfma_f32_16x16x32_bf16(af[m], bfv[n], acc[m][n], 0, 0, 0);
        }
    }

    const int r0 = (lane >> 4) * 4;
    const int cl = lane & 15;
    if constexpr (OUT_F32) {
        float* C = (float*)Cout;
#pragma unroll
        for (int m = 0; m < 4; ++m) {
            size_t row = m0 + wr + m * 16 + r0;
#pragma unroll
            for (int n = 0; n < 4; ++n) {
                size_t col = n0 + wc + n * 16 + cl;
                float bv = bias[col];
#pragma unroll
                for (int r = 0; r < 4; ++r)
                    C[(row + r) * (size_t)N + col] = acc[m][n][r] + bv;
            }
        }
    } else {
        u16* C = (u16*)Cout;
#pragma unroll
        for (int m = 0; m < 4; ++m) {
            size_t row = m0 + wr + m * 16 + r0;
#pragma unroll
            for (int n = 0; n < 4; ++n) {
                size_t col = n0 + wc + n * 16 + cl;
#pragma unroll
                for (int r = 0; r < 4; ++r)
                    C[(row + r) * (size_t)N + col] = f2bf(acc[m][n][r]);
            }
        }
    }
}

// ---------------- 256x256 pipelined GEMM (T2+T3+T4+T5) — GEMM1/QKV ----------------
// 512 thr = 8 waves (2M x 4N), per-wave C = 128x64. LDS = 4-slot ring per
// operand of [256][32] K-half tiles (128 KiB total, 1 block/CU).
// Phase (one K-half): vmcnt(8) -> s_barrier -> 12 ds_read_b128 ->
// stage kh+3 (4 global_load_lds) -> setprio(1) -> 32 MFMA -> setprio(0).
// Counted vmcnt: loads stay in flight across 3 phases; NEVER drained to 0 in
// the loop (T3/T4). Hazards: RAW (read slot staged 3 phases ago) <- own
// vmcnt(8) + barrier collects all waves; WAR (stage into slot read last
// phase) <- lgkmcnt-before-MFMA (compiler) + this phase's barrier precedes
// next phase's stage issue.
// LDS swizzle: 16B-chunk c stored at c ^ ((row>>1)&3) -> 2-way (free) on the
// 16-row fragment read; applied via pre-swizzled GLOBAL source + linear dest.
// Epilogue: V-third (tok>=2048) written transposed to VT; Q-third pre-scaled
// by 0.125*log2(e). MFMA order identical to the m97 kernel -> bit-identical C.
__global__ __launch_bounds__(512, 2)
void gemm256_kernel(const u16* __restrict__ A, const u16* __restrict__ BT,
                    u16* __restrict__ Cout, u16* __restrict__ VTout,
                    int M, int N, int K) {
    __shared__ u16 lds[65536];                 // 131072 B: A-ring 64KB | B-ring 64KB
    u16* lA = lds;
    u16* lB = lds + 32768;

    const int t = threadIdx.x, w = t >> 6, l = t & 63;
    const int g = l >> 4, ql = l & 15;
    const int wm = w >> 2, wn = w & 3;          // 2M x 4N wave grid
    const int nbx = N >> 8;
    int bid = blockIdx.x;
    int cpx = gridDim.x >> 3;                   // grid % 8 == 0
    int swz = (bid & 7) * cpx + (bid >> 3);
    const int bx = swz % nbx, by = swz / nbx;
    const size_t m0 = (size_t)by * 256, n0 = (size_t)bx * 256;

    const u16* Ag = A  + m0 * (size_t)K;
    const u16* Bg = BT + n0 * (size_t)K;

    // staging: per K-half tile [256][32]: 1024 16B-chunks; thread does ch = t, t+512.
    // source col pre-swizzled: chunk c of row r holds global chunk c ^ ((r>>1)&3).
    unsigned soff[2];
#pragma unroll
    for (int i = 0; i < 2; ++i) {
        int ch = i * 512 + t;
        int r = ch >> 2, c = ch & 3;
        soff[i] = (unsigned)(r * K + (c ^ ((r >> 1) & 3)) * 8);
    }

#define STAGE8(kh3) do {                                                           \
    int sl_ = (kh3) & 3;                                                           \
    _Pragma("unroll")                                                              \
    for (int i = 0; i < 2; ++i) {                                                  \
        async16(Ag + soff[i] + (unsigned)(kh3) * 32u, lA + sl_ * 8192 + (i * 512 + w * 64) * 8); \
        async16(Bg + soff[i] + (unsigned)(kh3) * 32u, lB + sl_ * 8192 + (i * 512 + w * 64) * 8); \
    } } while (0)

    STAGE8(0); STAGE8(1); STAGE8(2);           // prologue: 3 K-halves in flight

    f32x4 acc[8][4] = {};
    const int cswz = (g ^ ((ql >> 1) & 3)) * 8;    // read-side swizzle (uniform over m,n)
    const int arow = wm * 128 + ql;
    const int brow = wn * 64 + ql;

    auto phase = [&](int kh, int vm, bool st) {
        if (vm == 8)      asm volatile("s_waitcnt vmcnt(8)" ::: "memory");
        else if (vm == 4) asm volatile("s_waitcnt vmcnt(4)" ::: "memory");
        else              asm volatile("s_waitcnt vmcnt(0)" ::: "memory");
        __builtin_amdgcn_s_barrier();
        const u16* sA = lA + (kh & 3) * 8192;
        const u16* sB = lB + (kh & 3) * 8192;
        bf16x8 fa[8], fb[4];
#pragma unroll
        for (int m = 0; m < 8; ++m)
            fa[m] = *(const bf16x8*)&sA[(arow + m * 16) * 32 + cswz];
#pragma unroll
        for (int n = 0; n < 4; ++n)
            fb[n] = *(const bf16x8*)&sB[(brow + n * 16) * 32 + cswz];
        if (st) STAGE8(kh + 3);
        __builtin_amdgcn_s_setprio(1);
#pragma unroll
        for (int m = 0; m < 8; ++m)
#pragma unroll
            for (int n = 0; n < 4; ++n)
                acc[m][n] = __builtin_amdgcn_mfma_f32_16x16x32_bf16(fa[m], fb[n], acc[m][n], 0, 0, 0);
        __builtin_amdgcn_s_setprio(0);
    };

    const int KH = K >> 5;                     // K-halves of 32
#pragma unroll 1
    for (int kh = 0; kh < KH - 3; ++kh) phase(kh, 8, true);
    phase(KH - 3, 8, false);                   // tail: drain ring, vmcnt 8 -> 4 -> 0
    phase(KH - 2, 4, false);
    phase(KH - 1, 0, false);

    // epilogue (C/D: row = g*4 + r, col = ql per 16x16 fragment)
    const int r0 = g * 4;
    int tok0 = (int)(m0 % 3072);               // 256-tile stays within one third
    if (tok0 >= 2048) {
        // V third -> transposed VT[(b*16+h)*192 + ch][tok]
        int b = (int)(m0 / 3072);
#pragma unroll
        for (int m = 0; m < 8; ++m) {
            int tok = tok0 - 2048 + wm * 128 + m * 16 + r0;
#pragma unroll
            for (int n = 0; n < 4; ++n) {
                int col = (int)n0 + wn * 64 + n * 16 + ql;
                int h = col / 192, ch = col % 192;
                ushort4 v;
                v.x = f2bf(acc[m][n][0]);
                v.y = f2bf(acc[m][n][1]);
                v.z = f2bf(acc[m][n][2]);
                v.w = f2bf(acc[m][n][3]);
                *(ushort4*)(VTout + ((size_t)(b * 16 + h) * 192 + ch) * 1024 + tok) = v;
            }
        }
    } else {
        float qs = (tok0 < 1024) ? 0.1803368801111f : 1.0f;  // Q third: fold 0.125*log2(e)
#pragma unroll
        for (int m = 0; m < 8; ++m) {
            size_t row = m0 + wm * 128 + m * 16 + r0;
#pragma unroll
            for (int n = 0; n < 4; ++n) {
                size_t col = n0 + wn * 64 + n * 16 + ql;
#pragma unroll
                for (int r = 0; r < 4; ++r)
                    Cout[(row + r) * (size_t)N + col] = f2bf(acc[m][n][r] * qs);
            }
        }
    }
#undef STAGE8
}

// ---------------- flash attention (r9 version, unchanged) ----------------
__global__ __launch_bounds__(256, 2)
void attn_kernel(const u16* __restrict__ QKV, const u16* __restrict__ VT,
                 u16* __restrict__ comb) {
    __shared__ u16 lds[32768];                 // 65536 B: K|V|P
    u16* lK = lds;                             // [64][192] swz (12288 u16)
    u16* lV = lds + 12288;                     // [192][64] swz (12288 u16)
    u16* lP = lds + 24576;                     // 4 waves x [32][64] swz (8192 u16)

    const int t = threadIdx.x, w = t >> 6, lane = t & 63;
    const int bid = blockIdx.x;                // 1024 blocks
    const int gid = (bid & 7) * 128 + (bid >> 3);   // XCD-chunked
    const int bh = gid >> 3, qt = gid & 7;
    const int b = bh >> 4, h = bh & 15;

    const u16* Qg  = QKV + ((size_t)(b * 3072 + qt * 128 + w * 32)) * 3072 + h * 192;
    const u16* Kg  = QKV + ((size_t)(b * 3072 + 1024)) * 3072 + h * 192;
    const u16* VTg = VT + (size_t)bh * 192 * 1024;

    unsigned koff[6], voff[6];
#pragma unroll
    for (int i = 0; i < 6; ++i) {
        int ch = i * 256 + t;
        int kr = ch / 24, kc = ch % 24;             // K tile: 64 rows x 24 chunks(16B)
        koff[i] = kr * 3072 + (kc ^ (kr & 7)) * 8;
        int vr = ch >> 3, vc = ch & 7;              // V tile: 192 rows x 8 chunks
        voff[i] = vr * 1024 + (vc ^ (vr & 7)) * 8;
    }

#define STAGE_K(kt) do {                                                          \
    _Pragma("unroll")                                                             \
    for (int i = 0; i < 6; ++i)                                                   \
        async16(Kg + koff[i] + (unsigned)(kt) * 196608u, lK + (i * 256 + w * 64) * 8); \
    } while (0)
#define STAGE_V(kt) do {                                                          \
    _Pragma("unroll")                                                             \
    for (int i = 0; i < 6; ++i)                                                   \
        async16(VTg + voff[i] + (unsigned)(kt) * 64u, lV + (i * 256 + w * 64) * 8); \
    } while (0)

    STAGE_K(0);

    bf16x8 aq[2][6];
#pragma unroll
    for (int rg = 0; rg < 2; ++rg)
#pragma unroll
        for (int cs = 0; cs < 6; ++cs)
            aq[rg][cs] = *(const bf16x8*)(Qg + (size_t)(rg * 16 + (lane & 15)) * 3072
                                             + cs * 32 + (lane >> 4) * 8);

    f32x4 acc_o[2][12] = {};
    float m2[2][4], lsum[2][4];
#pragma unroll
    for (int rg = 0; rg < 2; ++rg)
#pragma unroll
        for (int r = 0; r < 4; ++r) { m2[rg][r] = -1e30f; lsum[rg][r] = 0.f; }
    u16* lPw = &lP[w * 2048];

#pragma unroll 1
    for (int it = 0; it < 16; ++it) {
        __syncthreads();                        // A: K[it] landed; PV reads of V[it-1] done
        STAGE_V(it);                            // V latency hides under QK^T+softmax

        f32x4 s[2][4] = {};
        __builtin_amdgcn_s_setprio(1);
#pragma unroll
        for (int kf = 0; kf < 4; ++kf) {
            const int krow = kf * 16 + (lane & 15);
#pragma unroll
            for (int cs = 0; cs < 6; ++cs) {
                bf16x8 bk = *(const bf16x8*)&lK[krow * 192 + ((cs * 4 + (lane >> 4)) ^ (krow & 7)) * 8];
                s[0][kf] = __builtin_amdgcn_mfma_f32_16x16x32_bf16(aq[0][cs], bk, s[0][kf], 0, 0, 0);
                s[1][kf] = __builtin_amdgcn_mfma_f32_16x16x32_bf16(aq[1][cs], bk, s[1][kf], 0, 0, 0);
            }
        }
        __builtin_amdgcn_s_setprio(0);

#pragma unroll
        for (int rg = 0; rg < 2; ++rg) {
            float mx[4];
            bool need = false;
#pragma unroll
            for (int r = 0; r < 4; ++r) {
                float m = fmaxf(fmaxf(s[rg][0][r], s[rg][1][r]), fmaxf(s[rg][2][r], s[rg][3][r]));
                mx[r] = dppmax16(m);
                need = need || (mx[r] > m2[rg][r] + 8.f);
            }
            if (__any((int)need)) {
#pragma unroll
                for (int r = 0; r < 4; ++r) {
                    float mn = fmaxf(m2[rg][r], mx[r]);
                    float fac = exp2f(m2[rg][r] - mn);
                    m2[rg][r] = mn;
                    lsum[rg][r] *= fac;
#pragma unroll
                    for (int df = 0; df < 12; ++df) acc_o[rg][df][r] *= fac;
                }
            }
#pragma unroll
            for (int r = 0; r < 4; ++r) {
                int q = rg * 16 + (lane >> 4) * 4 + r;
                int xr = (q & 7) << 3;
                float rs = 0.f;
#pragma unroll
                for (int kf = 0; kf < 4; ++kf) {
                    float p = exp2f(s[rg][kf][r] - m2[rg][r]);   // bounded by 2^8
                    rs += p;
                    lPw[q * 64 + ((kf * 16 + (lane & 15)) ^ xr)] = f2bf_rz(p);
                }
                lsum[rg][r] += dppsum16(rs);
            }
        }

        __syncthreads();                        // B: V[it] landed; K reads done
        if (it + 1 < 16) STAGE_K(it + 1);       // K latency hides under PV

        __builtin_amdgcn_s_setprio(1);
#pragma unroll
        for (int ks = 0; ks < 2; ++ks) {
            const int prow0 = (lane & 15), prow1 = 16 + (lane & 15);
            const int pcol = ks * 32 + (lane >> 4) * 8;
            bf16x8 pa0 = *(const bf16x8*)&lPw[prow0 * 64 + (pcol ^ ((prow0 & 7) << 3))];
            bf16x8 pa1 = *(const bf16x8*)&lPw[(prow1) * 64 + (pcol ^ ((prow1 & 7) << 3))];
#pragma unroll
            for (int df = 0; df < 12; ++df) {
                const int vrow = df * 16 + (lane & 15);
                bf16x8 bv = *(const bf16x8*)&lV[vrow * 64 + ((ks * 4 + (lane >> 4)) ^ (vrow & 7)) * 8];
                acc_o[0][df] = __builtin_amdgcn_mfma_f32_16x16x32_bf16(pa0, bv, acc_o[0][df], 0, 0, 0);
                acc_o[1][df] = __builtin_amdgcn_mfma_f32_16x16x32_bf16(pa1, bv, acc_o[1][df], 0, 0, 0);
            }
        }
        __builtin_amdgcn_s_setprio(0);
    }

    u16* dst = comb + ((size_t)(b * 1024 + qt * 128 + w * 32)) * 3072 + h * 192;
#pragma unroll
    for (int rg = 0; rg < 2; ++rg)
#pragma unroll
        for (int r = 0; r < 4; ++r) {
            int q = rg * 16 + (lane >> 4) * 4 + r;
            float invl = 1.0f / lsum[rg][r];
#pragma unroll
            for (int df = 0; df < 12; ++df)
                dst[(size_t)q * 3072 + df * 16 + (lane & 15)] = f2bf(acc_o[rg][df][r] * invl);
        }
#undef STAGE_K
#undef STAGE_V
}

// ---------------- host ----------------
extern "C" void kernel_launch(void* const* d_in, const int* in_sizes, int n_in,
                              void* d_out, int out_size, void* d_ws, size_t ws_size,
                              hipStream_t stream) {
    const float* X  = (const float*)d_in[0];   // [8,3072,1024]
    const float* W1 = (const float*)d_in[1];   // [1024,3072]
    const float* W2 = (const float*)d_in[2];   // [3072,1024]
    const float* Bb = (const float*)d_in[3];   // [1024]

    char* ws = (char*)d_ws;
    u16* Xb   = (u16*)(ws);                          // 50,331,648 B ; reused as comb
    u16* W1bT = (u16*)(ws + 50331648);               //  6,291,456 B  [3072][1024]
    u16* W2bT = (u16*)(ws + 56623104);               //  6,291,456 B  [1024][3072]
    u16* QKVb = (u16*)(ws + 62914560);               // 150,994,944 B [24576][3072] (V third unused)
    u16* VT   = (u16*)(ws + 213909504);              // 50,331,648 B  [128][192][1024]
    u16* comb = Xb;                                  // [8192][3072]

    cast_kernel<<<2048, 256, 0, stream>>>(X, Xb, (8 * 3072 * 1024) / 4);
    wtrans_kernel<<<dim3(3072 / 64, 1024 / 64), 256, 0, stream>>>(W1, W1bT, 1024, 3072);
    wtrans_kernel<<<dim3(1024 / 64, 3072 / 64), 256, 0, stream>>>(W2, W2bT, 3072, 1024);
    // GEMM1 (QKV): pipelined 256^2 kernel; V-third -> VT transposed, Q-third pre-scaled
    gemm256_kernel<<<(24576 / 256) * (3072 / 256), 512, 0, stream>>>(
        Xb, W1bT, QKVb, VT, 24576, 3072, 1024);
    attn_kernel<<<1024, 256, 0, stream>>>(QKVb, VT, comb);
    gemm_bt_kernel<true><<<(8192 / 128) * (1024 / 128), 256, 0, stream>>>(
        comb, W2bT, d_out, Bb, nullptr, 8192, 1024, 3072);
}